// Round 4
// baseline (1783.882 us; speedup 1.0000x reference)
//
#include <hip/hip_runtime.h>
#include <math.h>

// VMD: T = 2^20, K = 3, 50 iterations.
// Workspace layout (~26.1 MB):
//   [0,8MB)     f_hat  (float2, s-layout: s = k1*1024+k2, t(s) = ((k2^512)<<10)|k1)
//   [8,16MB)    h = f_hat - lam/2 at the kept iteration (float2, s-layout)
//   [16,24MB)   scratch (float2)  -- FFT intermediate; fallback path's lam aliases this
//   [24,26MB)   shadow: persistent: double[50][nblocks][8] partials (store-only);
//               fallback: acc double[8][64]
//   [26MB..)    bar: unsigned[4096] (hierarchical barrier: 64 group lines,
//               master at [2048], gen at [2080]) ; then omega0[16], omegaF[16]
// Fallback lam_old lives in d_out (dead until inverse passes overwrite it).

#define ALPHA_F 2000.0f
#define TAU_F   1e-7f

static __device__ __forceinline__ int lpad(int i) { return i + (i >> 5); }
static __device__ __forceinline__ int swz(int i)  { return ((i & 7) << 7) | (i >> 3); }

#define PADN 1057

// ---------------- 1024-point radix-4 Stockham FFT in LDS ----------------
template<int SIGN>   // -1 = forward (e^{-i}), +1 = inverse (e^{+i}, unscaled)
static __device__ void fft1024(float* Ar, float* Ai, float* Br, float* Bi)
{
  const int u = threadIdx.x;
#pragma unroll
  for (int st = 0; st < 5; ++st) {
    float *ir, *ii, *pr, *pi;
    if (st & 1) { ir = Br; ii = Bi; pr = Ar; pi = Ai; }
    else        { ir = Ar; ii = Ai; pr = Br; pi = Bi; }
    const int quarter = 1 << (2 * st);
    const int p = u & (quarter - 1);
    const int g = u >> (2 * st);

    float sw, cw;
    sincospif((float)(2 * p) * (1.0f / (float)(4 << (2 * st))), &sw, &cw);
    const float w1r = cw,                 w1i = (SIGN < 0) ? -sw : sw;
    const float w2r = w1r*w1r - w1i*w1i,  w2i = 2.0f*w1r*w1i;
    const float w3r = w2r*w1r - w2i*w1i,  w3i = w2r*w1i + w2i*w1r;

    float x0r = ir[lpad(u      )], x0i = ii[lpad(u      )];
    float x1r = ir[lpad(u + 256)], x1i = ii[lpad(u + 256)];
    float x2r = ir[lpad(u + 512)], x2i = ii[lpad(u + 512)];
    float x3r = ir[lpad(u + 768)], x3i = ii[lpad(u + 768)];

    float y1r = x1r*w1r - x1i*w1i, y1i = x1r*w1i + x1i*w1r;
    float y2r = x2r*w2r - x2i*w2i, y2i = x2r*w2i + x2i*w2r;
    float y3r = x3r*w3r - x3i*w3i, y3i = x3r*w3i + x3i*w3r;

    float t0r = x0r + y2r, t0i = x0i + y2i;
    float t1r = x0r - y2r, t1i = x0i - y2i;
    float t2r = y1r + y3r, t2i = y1i + y3i;
    float t3r = y1r - y3r, t3i = y1i - y3i;

    float o0r = t0r + t2r, o0i = t0i + t2i;
    float o2r = t0r - t2r, o2i = t0i - t2i;
    float o1r, o1i, o3r, o3i;
    if (SIGN < 0) {
      o1r = t1r + t3i; o1i = t1i - t3r;
      o3r = t1r - t3i; o3i = t1i + t3r;
    } else {
      o1r = t1r - t3i; o1i = t1i + t3r;
      o3r = t1r + t3i; o3i = t1i - t3r;
    }
    const int base = (g << (2 * st + 2)) + p;
    pr[lpad(base              )] = o0r; pi[lpad(base              )] = o0i;
    pr[lpad(base +     quarter)] = o1r; pi[lpad(base +     quarter)] = o1i;
    pr[lpad(base + 2 * quarter)] = o2r; pi[lpad(base + 2 * quarter)] = o2i;
    pr[lpad(base + 3 * quarter)] = o3r; pi[lpad(base + 3 * quarter)] = o3i;
    __syncthreads();
  }
}

// ---------------- init ----------------
__global__ __launch_bounds__(256) void k_init(double* shadow, float* omega0,
                                              unsigned* bar,
                                              const float* __restrict__ omega_init)
{
  int g = blockIdx.x * 256 + threadIdx.x;
  for (int j = g; j < 4096; j += 64 * 256) { shadow[j] = 0.0; bar[j] = 0u; }
  if (g < 3) omega0[g] = omega_init[g];
}

// ---------------- forward FFT ----------------
__global__ __launch_bounds__(256) void k_fwd_passA(const float* __restrict__ x,
                                                   float2* __restrict__ ws0)
{
  __shared__ float Ar[PADN], Ai[PADN], Br[PADN], Bi[PADN];
  const int b = swz(blockIdx.x);   // n2
  const int tid = threadIdx.x;
#pragma unroll
  for (int q = 0; q < 4; ++q) {
    int j = tid + 256 * q;         // n1
    Ar[lpad(j)] = x[(size_t)j * 1024 + b];
    Ai[lpad(j)] = 0.0f;
  }
  __syncthreads();
  fft1024<-1>(Ar, Ai, Br, Bi);
#pragma unroll
  for (int q = 0; q < 4; ++q) {
    int k1 = tid + 256 * q;
    int ph = b * k1;               // < 2^20, exact in fp32
    float s, c;
    sincospif((float)ph * (2.0f / 1048576.0f), &s, &c);
    float vr = Br[lpad(k1)], vi = Bi[lpad(k1)];
    ws0[(size_t)b * 1024 + k1] = make_float2(vr * c + vi * s, vi * c - vr * s);
  }
}

__global__ __launch_bounds__(256) void k_fwd_passB(const float2* __restrict__ ws0,
                                                   float2* __restrict__ fhat)
{
  __shared__ float Ar[PADN], Ai[PADN], Br[PADN], Bi[PADN];
  const int b = swz(blockIdx.x);   // k1
  const int tid = threadIdx.x;
#pragma unroll
  for (int q = 0; q < 4; ++q) {
    int j = tid + 256 * q;         // n2
    float2 v = ws0[(size_t)j * 1024 + b];
    Ar[lpad(j)] = v.x; Ai[lpad(j)] = v.y;
  }
  __syncthreads();
  fft1024<-1>(Ar, Ai, Br, Bi);
#pragma unroll
  for (int q = 0; q < 4; ++q) {
    int k2 = tid + 256 * q;
    fhat[(size_t)b * 1024 + k2] = make_float2(Br[lpad(k2)], Bi[lpad(k2)]);
  }
}

// ---------------- hierarchical, monotonic (reset-free) grid barrier ----------
// bar[ (bid>>3)*32 ] : per-group arrival counters (8 blocks/group, own line)
// bar[2048]          : master counter (one arrival per group)
// bar[2080]          : generation (monotonic phase)
static __device__ __forceinline__ void grid_barrier(unsigned* bar, int bid,
                                                    unsigned phase, unsigned nblocks)
{
  __syncthreads();
  if (threadIdx.x == 0) {
    const unsigned ng = nblocks >> 3;
    unsigned prev = __hip_atomic_fetch_add(&bar[(unsigned)(bid >> 3) * 32u], 1u,
                                           __ATOMIC_ACQ_REL, __HIP_MEMORY_SCOPE_AGENT);
    if (prev == 8u * phase - 1u) {
      unsigned p2 = __hip_atomic_fetch_add(&bar[2048], 1u,
                                           __ATOMIC_ACQ_REL, __HIP_MEMORY_SCOPE_AGENT);
      if (p2 == ng * phase - 1u)
        __hip_atomic_store(&bar[2080], phase, __ATOMIC_RELEASE,
                           __HIP_MEMORY_SCOPE_AGENT);
    }
    while (__hip_atomic_load(&bar[2080], __ATOMIC_ACQUIRE,
                             __HIP_MEMORY_SCOPE_AGENT) < phase)
      __builtin_amdgcn_s_sleep(8);
  }
  __syncthreads();
}

// ---------------- persistent 50-iteration kernel ----------------
// NQ float4s (= 2*NQ complex) per thread; grid = 524288/(256*NQ) blocks of 256.
template<int NQ>
__global__ __launch_bounds__(256, (NQ == 4) ? 2 : 1) void k_vmd_persist(
    const float2* __restrict__ fhat, float2* __restrict__ h_out,
    const float* __restrict__ omega0, float* __restrict__ omega_final,
    double* __restrict__ shadow, unsigned* bar)
{
  const int NT   = 524288 / NQ;              // total threads = float4 stride
  const int NBLK = NT / 256;                 // 512 (NQ=4) or 256 (NQ=8)
  const int SLOT = NBLK * 8;                 // doubles per iteration
  const int RGAT = NBLK / 32;                // gather loads per thread
  const int tid = threadIdx.x;
  const int bid = blockIdx.x;
  const int gthread = bid * 256 + tid;

  __shared__ float  sb[8];
  __shared__ double red[256];

  float4 f[NQ], lam[NQ], lamp[NQ];
  float  frq[NQ][2];
#pragma unroll
  for (int q = 0; q < NQ; ++q) {
    const int f4i = gthread + q * NT;        // coalesced grid-stride
    f[q] = ((const float4*)fhat)[f4i];
    lam[q] = make_float4(0.f, 0.f, 0.f, 0.f);
    lamp[q] = lam[q];
#pragma unroll
    for (int c = 0; c < 2; ++c) {
      const int s = f4i * 2 + c;
      const int tt = (((s & 1023) ^ 512) << 10) | (s >> 10);
      frq[q][c] = (float)tt * (1.0f / 1048576.0f) - 0.5f;
    }
  }
  if (tid == 0) { sb[0] = omega0[0]; sb[1] = omega0[1]; sb[2] = omega0[2]; }
  __syncthreads();
  float om0 = sb[0], om1 = sb[1], om2 = sb[2];
  float pm0 = 0.f, pm1 = 0.f, pm2 = 0.f;
  const float TAU2 = TAU_F * TAU_F;

  for (int n = 0; n < 50; ++n) {
    const bool check = (n % 10 == 0) && (n > 0);
    const bool snap  = (n % 10) == 9;
    const bool hw    = check || (n == 49);   // freeze-candidate entry

    if (snap) {
#pragma unroll
      for (int q = 0; q < NQ; ++q) lamp[q] = lam[q];
      pm0 = om0; pm1 = om1; pm2 = om2;
    }
    if (hw) {
#pragma unroll
      for (int q = 0; q < NQ; ++q) {
        const int f4i = gthread + q * NT;
        float4 hv;
        hv.x = f[q].x - 0.5f * lam[q].x; hv.y = f[q].y - 0.5f * lam[q].y;
        hv.z = f[q].z - 0.5f * lam[q].z; hv.w = f[q].w - 0.5f * lam[q].w;
        ((float4*)h_out)[f4i] = hv;
      }
      if (gthread == 0) {
        omega_final[0] = om0; omega_final[1] = om1; omega_final[2] = om2;
      }
    }

    double p0 = 0, p1 = 0, p2 = 0, p3 = 0, p4 = 0, p5 = 0, p6 = 0, p7 = 0;
#pragma unroll
    for (int q = 0; q < NQ; ++q) {
#pragma unroll
      for (int c = 0; c < 2; ++c) {
        const float fr = c ? f[q].z : f[q].x,     fi = c ? f[q].w : f[q].y;
        const float lr = c ? lam[q].z : lam[q].x, li = c ? lam[q].w : lam[q].y;
        const float freq = frq[q][c];
        float a0 = freq - om0, a1 = freq - om1, a2 = freq - om2;
        float d0 = a0 * a0, d1 = a1 * a1, d2 = a2 * a2;
        float w0 = 1.0f / (1.0f + ALPHA_F * (d0 + d1 + TAU2));
        float w1 = 1.0f / (1.0f + ALPHA_F * (d0 + d1 + d2 + TAU2));
        float w2 = 1.0f / (1.0f + ALPHA_F * (d1 + d2 + TAU2));
        float hr = fr - 0.5f * lr, hi = fi - 0.5f * li;
        float g = hr * hr + hi * hi;
        float gw0 = g * w0 * w0, gw1 = g * w1 * w1, gw2 = g * w2 * w2;
        p0 += (double)(freq * gw0); p1 += (double)(freq * gw1); p2 += (double)(freq * gw2);
        p3 += (double)gw0;          p4 += (double)gw1;          p5 += (double)gw2;
        float S = w0 + w1 + w2;
        float nlr = lr + TAU_F * (hr * S - fr);
        float nli = li + TAU_F * (hi * S - fi);
        if (c == 0) { lam[q].x = nlr; lam[q].y = nli; }
        else        { lam[q].z = nlr; lam[q].w = nli; }
        if (check) {
          const float plr = c ? lamp[q].z : lamp[q].x, pli = c ? lamp[q].w : lamp[q].y;
          float hpr = fr - 0.5f * plr, hpi = fi - 0.5f * pli;
          float b0 = freq - pm0, b1 = freq - pm1, b2 = freq - pm2;
          float e0 = b0 * b0, e1 = b1 * b1, e2 = b2 * b2;
          float v0 = 1.0f / (1.0f + ALPHA_F * (e0 + e1 + TAU2));
          float v1 = 1.0f / (1.0f + ALPHA_F * (e0 + e1 + e2 + TAU2));
          float v2 = 1.0f / (1.0f + ALPHA_F * (e1 + e2 + TAU2));
          float dr, di;
          dr = hr * w0 - hpr * v0; di = hi * w0 - hpi * v0; p6 += (double)(dr * dr + di * di);
          dr = hr * w1 - hpr * v1; di = hi * w1 - hpi * v1; p6 += (double)(dr * dr + di * di);
          dr = hr * w2 - hpr * v2; di = hi * w2 - hpi * v2; p6 += (double)(dr * dr + di * di);
          float gp = hpr * hpr + hpi * hpi;
          p7 += (double)(gp * (v0 * v0 + v1 * v1 + v2 * v2));
        }
      }
    }

    // block-level reduce: wave shuffle -> LDS -> 8 block partials
    {
      double pv[8] = { p0, p1, p2, p3, p4, p5, p6, p7 };
      const int lane = tid & 63, wv = tid >> 6;
#pragma unroll
      for (int j = 0; j < 8; ++j) {
        double v = pv[j];
        for (int off = 32; off; off >>= 1) v += __shfl_down(v, off, 64);
        if (lane == 0) red[wv * 8 + j] = v;
      }
    }
    __syncthreads();
    // store partials to this block's own slot -- zero contention
    if (tid < 8) {
      double s = red[tid] + red[8 + tid] + red[16 + tid] + red[24 + tid];
      __hip_atomic_store(&shadow[(size_t)n * SLOT + bid * 8 + tid], s,
                         __ATOMIC_RELAXED, __HIP_MEMORY_SCOPE_AGENT);
    }

    grid_barrier(bar, bid, (unsigned)(n + 1), (unsigned)NBLK);

    // gather all NBLK*8 partials (coalesced, fixed order -> identical in all blocks)
    {
      double gsum = 0.0;
#pragma unroll
      for (int r = 0; r < RGAT; ++r)
        gsum += __hip_atomic_load(&shadow[(size_t)n * SLOT + tid + 256 * r],
                                  __ATOMIC_RELAXED, __HIP_MEMORY_SCOPE_AGENT);
      red[tid] = gsum;
    }
    __syncthreads();
#pragma unroll
    for (int s = 128; s >= 8; s >>= 1) {
      if (tid < s) red[tid] += red[tid + s];
      __syncthreads();
    }
    if (tid == 0) {
      float no0 = (float)(red[0] / red[3]);
      float no1 = (float)(red[1] / red[4]);
      float no2 = (float)(red[2] / red[5]);
      float conv = 0.0f;
      if (check) {
        bool ud_ok = red[6] < 1e-6 * red[7];
        float omd = (fabsf(no0 - no2) + fabsf(no1 - no0) + fabsf(no2 - no1)) * (1.0f / 3.0f);
        if (ud_ok && omd < 1e-6f) conv = 1.0f;
      }
      sb[0] = no0; sb[1] = no1; sb[2] = no2; sb[3] = conv;
    }
    __syncthreads();
    om0 = sb[0]; om1 = sb[1]; om2 = sb[2];
    if (sb[3] != 0.0f) break;   // grid-uniform: identical sums in every block
  }
}

// ---------------- fallback: round-1 proven per-iteration kernel ----------------
static __device__ __forceinline__ bool conv_at(const double* __restrict__ acc, int m)
{
  double a6 = acc[6 * 64 + m], a7 = acc[7 * 64 + m];
  if (!(a6 < 1e-6 * a7)) return false;
  float o0 = (float)(acc[0 * 64 + m] / acc[3 * 64 + m]);
  float o1 = (float)(acc[1 * 64 + m] / acc[4 * 64 + m]);
  float o2 = (float)(acc[2 * 64 + m] / acc[5 * 64 + m]);
  float omd = (fabsf(o0 - o2) + fabsf(o1 - o0) + fabsf(o2 - o1)) * (1.0f / 3.0f);
  return omd < 1e-6f;
}

__global__ __launch_bounds__(256) void k_vmd_iter(
    const float2* __restrict__ fhat, float2* __restrict__ lam,
    float2* __restrict__ lam_old, const float* __restrict__ omega0,
    double* __restrict__ acc, float2* __restrict__ h_out,
    float* __restrict__ omega_final, int n)
{
  __shared__ float sb[8];
  __shared__ double red[32];
  const int tid = threadIdx.x;
  const bool check = (n > 0) && (n % 10 == 0);
  const bool wold  = ((n % 10) == 9) || check;
  const bool hw    = check || (n == 49);
  const bool first = (n == 0);

  if (tid == 0) {
    bool done = false;
    for (int m = 10; m < n; m += 10) if (conv_at(acc, m)) { done = true; break; }
    if (first) { sb[0] = omega0[0]; sb[1] = omega0[1]; sb[2] = omega0[2]; }
    else {
      sb[0] = (float)(acc[0 * 64 + n - 1] / acc[3 * 64 + n - 1]);
      sb[1] = (float)(acc[1 * 64 + n - 1] / acc[4 * 64 + n - 1]);
      sb[2] = (float)(acc[2 * 64 + n - 1] / acc[5 * 64 + n - 1]);
    }
    if (check) {
      sb[3] = (float)(acc[0 * 64 + n - 2] / acc[3 * 64 + n - 2]);
      sb[4] = (float)(acc[1 * 64 + n - 2] / acc[4 * 64 + n - 2]);
      sb[5] = (float)(acc[2 * 64 + n - 2] / acc[5 * 64 + n - 2]);
    } else { sb[3] = 0.f; sb[4] = 0.f; sb[5] = 0.f; }
    sb[6] = done ? 1.0f : 0.0f;
  }
  __syncthreads();
  if (sb[6] != 0.0f) return;   // frozen
  const float om0 = sb[0], om1 = sb[1], om2 = sb[2];
  const float pm0 = sb[3], pm1 = sb[4], pm2 = sb[5];
  if (hw && blockIdx.x == 0 && tid == 0) {
    omega_final[0] = om0; omega_final[1] = om1; omega_final[2] = om2;
  }

  const float TAU2 = TAU_F * TAU_F;
  double p0 = 0, p1 = 0, p2 = 0, p3 = 0, p4 = 0, p5 = 0, p6 = 0, p7 = 0;
  const int gid = blockIdx.x * 256 + tid;

#pragma unroll
  for (int h2 = 0; h2 < 2; ++h2) {
    const int f4i = gid * 2 + h2;
    const float4 fv = ((const float4*)fhat)[f4i];
    float4 lv;
    if (first) lv = make_float4(0.f, 0.f, 0.f, 0.f);
    else       lv = ((const float4*)lam)[f4i];
    float4 lov = make_float4(0.f, 0.f, 0.f, 0.f);
    if (check)  lov = ((const float4*)lam_old)[f4i];
    if (hw) {
      float4 hv;
      hv.x = fv.x - 0.5f * lv.x; hv.y = fv.y - 0.5f * lv.y;
      hv.z = fv.z - 0.5f * lv.z; hv.w = fv.w - 0.5f * lv.w;
      ((float4*)h_out)[f4i] = hv;
    }
    float4 nl;
#pragma unroll
    for (int c = 0; c < 2; ++c) {
      const int s = f4i * 2 + c;
      const float fr = c ? fv.z : fv.x, fi = c ? fv.w : fv.y;
      const float lr = c ? lv.z : lv.x, li = c ? lv.w : lv.y;
      const int k2s = s & 1023, k1s = s >> 10;
      const int tt = ((k2s ^ 512) << 10) | k1s;
      const float freq = (float)tt * (1.0f / 1048576.0f) - 0.5f;
      float a0 = freq - om0, a1 = freq - om1, a2 = freq - om2;
      float d0 = a0 * a0, d1 = a1 * a1, d2 = a2 * a2;
      float w0 = 1.0f / (1.0f + ALPHA_F * (d0 + d1 + TAU2));
      float w1 = 1.0f / (1.0f + ALPHA_F * (d0 + d1 + d2 + TAU2));
      float w2 = 1.0f / (1.0f + ALPHA_F * (d1 + d2 + TAU2));
      float hr = fr - 0.5f * lr, hi = fi - 0.5f * li;
      float g = hr * hr + hi * hi;
      float gw0 = g * w0 * w0, gw1 = g * w1 * w1, gw2 = g * w2 * w2;
      p0 += (double)(freq * gw0); p1 += (double)(freq * gw1); p2 += (double)(freq * gw2);
      p3 += (double)gw0;          p4 += (double)gw1;          p5 += (double)gw2;
      float S = w0 + w1 + w2;
      float nlr = lr + TAU_F * (hr * S - fr);
      float nli = li + TAU_F * (hi * S - fi);
      if (c == 0) { nl.x = nlr; nl.y = nli; } else { nl.z = nlr; nl.w = nli; }
      if (check) {
        const float plr = c ? lov.z : lov.x, pli = c ? lov.w : lov.y;
        float hpr = fr - 0.5f * plr, hpi = fi - 0.5f * pli;
        float b0 = freq - pm0, b1 = freq - pm1, b2 = freq - pm2;
        float e0 = b0 * b0, e1 = b1 * b1, e2 = b2 * b2;
        float v0 = 1.0f / (1.0f + ALPHA_F * (e0 + e1 + TAU2));
        float v1 = 1.0f / (1.0f + ALPHA_F * (e0 + e1 + e2 + TAU2));
        float v2 = 1.0f / (1.0f + ALPHA_F * (e1 + e2 + TAU2));
        float dr, di;
        dr = hr * w0 - hpr * v0; di = hi * w0 - hpi * v0; p6 += (double)(dr * dr + di * di);
        dr = hr * w1 - hpr * v1; di = hi * w1 - hpi * v1; p6 += (double)(dr * dr + di * di);
        dr = hr * w2 - hpr * v2; di = hi * w2 - hpi * v2; p6 += (double)(dr * dr + di * di);
        float gp = hpr * hpr + hpi * hpi;
        p7 += (double)(gp * (v0 * v0 + v1 * v1 + v2 * v2));
      }
    }
    ((float4*)lam)[f4i] = nl;
    if (wold) ((float4*)lam_old)[f4i] = lv;
  }

  {
    double pv[8] = { p0, p1, p2, p3, p4, p5, p6, p7 };
    const int lane = tid & 63, wv = tid >> 6;
#pragma unroll
    for (int j = 0; j < 8; ++j) {
      double v = pv[j];
      for (int off = 32; off; off >>= 1) v += __shfl_down(v, off, 64);
      if (lane == 0) red[wv * 8 + j] = v;
    }
  }
  __syncthreads();
  if (tid < 8) {
    double ssum = red[tid] + red[8 + tid] + red[16 + tid] + red[24 + tid];
    unsafeAtomicAdd(&acc[tid * 64 + n], ssum);
  }
}

// ---------------- inverse FFT (per mode) ----------------
__global__ __launch_bounds__(256) void k_inv_passA(
    const float2* __restrict__ h, const float* __restrict__ omega_final,
    float2* __restrict__ ws0, int mode)
{
  __shared__ float Ar[PADN], Ai[PADN], Br[PADN], Bi[PADN];
  __shared__ float som[3];
  const int tid = threadIdx.x;
  if (tid == 0) { som[0] = omega_final[0]; som[1] = omega_final[1]; som[2] = omega_final[2]; }
  __syncthreads();
  const float om0 = som[0], om1 = som[1], om2 = som[2];
  const int b = swz(blockIdx.x);   // n2
  const float TAU2 = TAU_F * TAU_F;
#pragma unroll
  for (int q = 0; q < 4; ++q) {
    int j = tid + 256 * q;         // n1 ; ifftshift cancels: contiguous load
    float2 hv = h[(size_t)b * 1024 + j];
    int tt = ((j ^ 512) << 10) | b;
    float freq = (float)tt * (1.0f / 1048576.0f) - 0.5f;
    float a0 = freq - om0, a1 = freq - om1, a2 = freq - om2;
    float d0 = a0 * a0, d1 = a1 * a1, d2 = a2 * a2;
    float den = (mode == 0) ? (d0 + d1) : (mode == 1) ? (d0 + d1 + d2) : (d1 + d2);
    float wk = 1.0f / (1.0f + ALPHA_F * (den + TAU2));
    Ar[lpad(j)] = hv.x * wk; Ai[lpad(j)] = hv.y * wk;
  }
  __syncthreads();
  fft1024<1>(Ar, Ai, Br, Bi);
#pragma unroll
  for (int q = 0; q < 4; ++q) {
    int m1 = tid + 256 * q;
    int ph = b * m1;
    float s, c;
    sincospif((float)ph * (2.0f / 1048576.0f), &s, &c);
    float vr = Br[lpad(m1)], vi = Bi[lpad(m1)];
    ws0[(size_t)b * 1024 + m1] = make_float2(vr * c - vi * s, vi * c + vr * s);
  }
}

__global__ __launch_bounds__(256) void k_inv_passB(const float2* __restrict__ ws0,
                                                   float* __restrict__ out)
{
  __shared__ float Ar[PADN], Ai[PADN], Br[PADN], Bi[PADN];
  const int b = swz(blockIdx.x);   // m1
  const int tid = threadIdx.x;
#pragma unroll
  for (int q = 0; q < 4; ++q) {
    int j = tid + 256 * q;         // n2
    float2 v = ws0[(size_t)j * 1024 + b];
    Ar[lpad(j)] = v.x; Ai[lpad(j)] = v.y;
  }
  __syncthreads();
  fft1024<1>(Ar, Ai, Br, Bi);
#pragma unroll
  for (int q = 0; q < 4; ++q) {
    int m2 = tid + 256 * q;
    out[(size_t)m2 * 1024 + b] = Br[lpad(m2)] * (1.0f / 1048576.0f);
  }
}

// ---------------- host launch ----------------
extern "C" void kernel_launch(void* const* d_in, const int* in_sizes, int n_in,
                              void* d_out, int out_size, void* d_ws, size_t ws_size,
                              hipStream_t stream)
{
  (void)in_sizes; (void)n_in; (void)out_size; (void)ws_size;
  const float* x       = (const float*)d_in[0];
  const float* om_init = (const float*)d_in[1];
  float* out = (float*)d_out;

  char* w = (char*)d_ws;
  const size_t MB = 1024ull * 1024ull;
  float2*   fhat    = (float2*)(w);
  float2*   h       = (float2*)(w + 8 * MB);
  float2*   scratch = (float2*)(w + 16 * MB);
  double*   shadow  = (double*)(w + 24 * MB);            // up to 50*512*8 doubles
  unsigned* bar     = (unsigned*)(w + 26 * MB);          // 4096 uints
  float*    omega0  = (float*)(w + 26 * MB + 16 * 1024);
  float*    omegaF  = omega0 + 16;

  k_init<<<64, 256, 0, stream>>>(shadow, omega0, bar, om_init);
  k_fwd_passA<<<1024, 256, 0, stream>>>(x, scratch);
  k_fwd_passB<<<1024, 256, 0, stream>>>(scratch, fhat);

  {
    void* p0 = (void*)fhat;   void* p1 = (void*)h;
    void* p2 = (void*)omega0; void* p3 = (void*)omegaF;
    void* p4 = (void*)shadow; void* p5 = (void*)bar;
    void* args[6] = { &p0, &p1, &p2, &p3, &p4, &p5 };

    hipError_t e = hipLaunchCooperativeKernel((void*)&k_vmd_persist<4>, dim3(512),
                                              dim3(256), args, 0, stream);
    if (e != hipSuccess) {
      (void)hipGetLastError();
      e = hipLaunchCooperativeKernel((void*)&k_vmd_persist<8>, dim3(256),
                                     dim3(256), args, 0, stream);
    }
    if (e != hipSuccess) {
      (void)hipGetLastError();
      // Proven round-1 path: lam aliases FFT scratch; lam_old lives in d_out
      // (dead until the inverse passes fully overwrite it).
      float2* lam     = scratch;
      float2* lam_old = (float2*)d_out;
      for (int n = 0; n < 50; ++n)
        k_vmd_iter<<<1024, 256, 0, stream>>>(fhat, lam, lam_old, omega0,
                                             shadow, h, omegaF, n);
    }
  }

  for (int mode = 0; mode < 3; ++mode) {
    k_inv_passA<<<1024, 256, 0, stream>>>(h, omegaF, scratch, mode);
    k_inv_passB<<<1024, 256, 0, stream>>>(scratch, out + (size_t)mode * 1048576ull);
  }
}

// Round 5
// 656.119 us; speedup vs baseline: 2.7188x; 2.7188x over previous
//
#include <hip/hip_runtime.h>
#include <math.h>

// VMD: T = 2^20, K = 3, 50 iterations.
// Key algebra: lam0 = 0 and lam_new = lam*(stuff(freq,omega)) + f_hat*(stuff(freq,omega))
// ==> lam(t) = c(freq_t) * f_hat(t) with c REAL:
//     c' = c + TAU*(S*(1 - c/2) - 1),  S = w0+w1+w2,  w_k = 1/(1+ALPHA*denom_k)
// u_hat_k = f_hat*(1-c/2)*w_k ; all omega sums use E = |f_hat|^2 only.
// Per-iteration sync = kernel dispatch boundary (HW CP sync beats any in-kernel
// grid barrier on this chip -- measured rounds 3/4).
//
// Workspace (~32.05 MB):
//   [0,8MB)    f_hat (float2, s-layout: s = k1*1024+k2, t(s) = ((k2^512)<<10)|k1)
//   [8,12MB)   E = |f_hat|^2 (float)
//   [12,16MB)  c (float)
//   [16,20MB)  c_snap (float)   -- c at entry of iters 9,19,29,39
//   [20,24MB)  c_keep (float)   -- c at entry of kept iter (10/20/30/40/49)
//   [24,32MB)  scratch (float2) -- FFT intermediate
//   [32MB..)   P0/P1 ping-pong partials double[256][8]; omhist float[50*4];
//              omegaF float[4]; done int

#define ALPHA_F 2000.0f
#define TAU_F   1e-7f

static __device__ __forceinline__ int lpad(int i) { return i + (i >> 5); }
static __device__ __forceinline__ int swz(int i)  { return ((i & 7) << 7) | (i >> 3); }

#define PADN 1057

// ---------------- 1024-point radix-4 Stockham FFT in LDS ----------------
template<int SIGN>   // -1 = forward (e^{-i}), +1 = inverse (e^{+i}, unscaled)
static __device__ void fft1024(float* Ar, float* Ai, float* Br, float* Bi)
{
  const int u = threadIdx.x;
#pragma unroll
  for (int st = 0; st < 5; ++st) {
    float *ir, *ii, *pr, *pi;
    if (st & 1) { ir = Br; ii = Bi; pr = Ar; pi = Ai; }
    else        { ir = Ar; ii = Ai; pr = Br; pi = Bi; }
    const int quarter = 1 << (2 * st);
    const int p = u & (quarter - 1);
    const int g = u >> (2 * st);

    float sw, cw;
    sincospif((float)(2 * p) * (1.0f / (float)(4 << (2 * st))), &sw, &cw);
    const float w1r = cw,                 w1i = (SIGN < 0) ? -sw : sw;
    const float w2r = w1r*w1r - w1i*w1i,  w2i = 2.0f*w1r*w1i;
    const float w3r = w2r*w1r - w2i*w1i,  w3i = w2r*w1i + w2i*w1r;

    float x0r = ir[lpad(u      )], x0i = ii[lpad(u      )];
    float x1r = ir[lpad(u + 256)], x1i = ii[lpad(u + 256)];
    float x2r = ir[lpad(u + 512)], x2i = ii[lpad(u + 512)];
    float x3r = ir[lpad(u + 768)], x3i = ii[lpad(u + 768)];

    float y1r = x1r*w1r - x1i*w1i, y1i = x1r*w1i + x1i*w1r;
    float y2r = x2r*w2r - x2i*w2i, y2i = x2r*w2i + x2i*w2r;
    float y3r = x3r*w3r - x3i*w3i, y3i = x3r*w3i + x3i*w3r;

    float t0r = x0r + y2r, t0i = x0i + y2i;
    float t1r = x0r - y2r, t1i = x0i - y2i;
    float t2r = y1r + y3r, t2i = y1i + y3i;
    float t3r = y1r - y3r, t3i = y1i - y3i;

    float o0r = t0r + t2r, o0i = t0i + t2i;
    float o2r = t0r - t2r, o2i = t0i - t2i;
    float o1r, o1i, o3r, o3i;
    if (SIGN < 0) {
      o1r = t1r + t3i; o1i = t1i - t3r;
      o3r = t1r - t3i; o3i = t1i + t3r;
    } else {
      o1r = t1r - t3i; o1i = t1i + t3r;
      o3r = t1r + t3i; o3i = t1i - t3r;
    }
    const int base = (g << (2 * st + 2)) + p;
    pr[lpad(base              )] = o0r; pi[lpad(base              )] = o0i;
    pr[lpad(base +     quarter)] = o1r; pi[lpad(base +     quarter)] = o1i;
    pr[lpad(base + 2 * quarter)] = o2r; pi[lpad(base + 2 * quarter)] = o2i;
    pr[lpad(base + 3 * quarter)] = o3r; pi[lpad(base + 3 * quarter)] = o3i;
    __syncthreads();
  }
}

// ---------------- forward FFT ----------------
__global__ __launch_bounds__(256) void k_fwd_passA(const float* __restrict__ x,
                                                   float2* __restrict__ ws0)
{
  __shared__ float Ar[PADN], Ai[PADN], Br[PADN], Bi[PADN];
  const int b = swz(blockIdx.x);   // n2
  const int tid = threadIdx.x;
#pragma unroll
  for (int q = 0; q < 4; ++q) {
    int j = tid + 256 * q;         // n1
    Ar[lpad(j)] = x[(size_t)j * 1024 + b];
    Ai[lpad(j)] = 0.0f;
  }
  __syncthreads();
  fft1024<-1>(Ar, Ai, Br, Bi);
#pragma unroll
  for (int q = 0; q < 4; ++q) {
    int k1 = tid + 256 * q;
    int ph = b * k1;               // < 2^20, exact in fp32
    float s, c;
    sincospif((float)ph * (2.0f / 1048576.0f), &s, &c);
    float vr = Br[lpad(k1)], vi = Bi[lpad(k1)];
    ws0[(size_t)b * 1024 + k1] = make_float2(vr * c + vi * s, vi * c - vr * s);
  }
}

__global__ __launch_bounds__(256) void k_fwd_passB(const float2* __restrict__ ws0,
                                                   float2* __restrict__ fhat,
                                                   float* __restrict__ E)
{
  __shared__ float Ar[PADN], Ai[PADN], Br[PADN], Bi[PADN];
  const int b = swz(blockIdx.x);   // k1
  const int tid = threadIdx.x;
#pragma unroll
  for (int q = 0; q < 4; ++q) {
    int j = tid + 256 * q;         // n2
    float2 v = ws0[(size_t)j * 1024 + b];
    Ar[lpad(j)] = v.x; Ai[lpad(j)] = v.y;
  }
  __syncthreads();
  fft1024<-1>(Ar, Ai, Br, Bi);
#pragma unroll
  for (int q = 0; q < 4; ++q) {
    int k2 = tid + 256 * q;
    float vr = Br[lpad(k2)], vi = Bi[lpad(k2)];
    fhat[(size_t)b * 1024 + k2] = make_float2(vr, vi);
    E[(size_t)b * 1024 + k2] = vr * vr + vi * vi;
  }
}

// ---------------- one VMD iteration (dispatch-boundary-synced) ----------------
// 256 blocks x 1024 threads; 4 elements (one float4) per thread.
// Kernel n: reduce partials[n-1] (identical, deterministic in every block) ->
// omega entering step n; evaluate convergence of check n-1 if applicable;
// step c; emit partials[n].
__global__ __launch_bounds__(1024) void k_iter(
    const float4* __restrict__ E4, float4* __restrict__ c4,
    float4* __restrict__ csnap, float4* __restrict__ ckeep,
    const double* __restrict__ pin, double* __restrict__ pout,
    float* __restrict__ omhist, float* __restrict__ omegaF,
    int* __restrict__ done, const float* __restrict__ omega_init, int n)
{
  __shared__ double red[1024];
  __shared__ float sb[8];
  const int tid = threadIdx.x, bid = blockIdx.x;
  const int gid = bid * 1024 + tid;

  const bool conveval  = (n == 11) || (n == 21) || (n == 31) || (n == 41);
  const bool checkcomp = (n == 10) || (n == 20) || (n == 30) || (n == 40);
  const bool snap      = (n == 9)  || (n == 19) || (n == 29) || (n == 39);
  const bool keep      = checkcomp || (n == 49);

  if (n == 0) {
    if (tid == 0) {
      sb[0] = omega_init[0]; sb[1] = omega_init[1]; sb[2] = omega_init[2];
      if (bid == 0) done[0] = 0;    // clear poisoned flag for later dispatches
    }
    __syncthreads();
  } else {
    if (tid == 0) sb[4] = (done[0] != 0) ? 1.0f : 0.0f;
    __syncthreads();
    if (sb[4] != 0.0f) return;      // frozen since an earlier converged check

    // deterministic reduce of 256*8 partials (identical order in every block)
    red[tid] = pin[tid] + pin[tid + 1024];
    __syncthreads();
#pragma unroll
    for (int s = 512; s >= 8; s >>= 1) {
      if (tid < s) red[tid] += red[tid + s];
      __syncthreads();
    }
    if (tid == 0) {
      float no0 = (float)(red[0] / red[3]);
      float no1 = (float)(red[1] / red[4]);
      float no2 = (float)(red[2] / red[5]);
      float conv = 0.0f;
      if (conveval) {
        bool ud_ok = red[6] < 1e-6 * red[7];
        float omd = (fabsf(no0 - no2) + fabsf(no1 - no0) + fabsf(no2 - no1)) * (1.0f / 3.0f);
        if (ud_ok && omd < 1e-6f) conv = 1.0f;
      }
      sb[0] = no0; sb[1] = no1; sb[2] = no2; sb[3] = conv;
      if (checkcomp) {              // previous omega for u_diff at this check
        sb[5] = omhist[(n - 1) * 4 + 0];
        sb[6] = omhist[(n - 1) * 4 + 1];
        sb[7] = omhist[(n - 1) * 4 + 2];
      }
    }
    __syncthreads();
    if (sb[3] != 0.0f) {            // check at n-1 converged: freeze from now on
      if (bid == 0 && tid == 0) done[0] = 1;
      return;
    }
  }

  const float om0 = sb[0], om1 = sb[1], om2 = sb[2];
  if (bid == 0 && tid == 0) {
    omhist[n * 4 + 0] = om0; omhist[n * 4 + 1] = om1; omhist[n * 4 + 2] = om2;
    if (keep) { omegaF[0] = om0; omegaF[1] = om1; omegaF[2] = om2; }
  }
  float pm0 = 0.f, pm1 = 0.f, pm2 = 0.f;
  if (checkcomp) { pm0 = sb[5]; pm1 = sb[6]; pm2 = sb[7]; }

  const float TAU2 = TAU_F * TAU_F;
  const float4 Ev = E4[gid];
  float4 cv = make_float4(0.f, 0.f, 0.f, 0.f);
  if (n > 0) cv = c4[gid];
  float4 csv = make_float4(0.f, 0.f, 0.f, 0.f);
  if (checkcomp) csv = csnap[gid];
  if (keep) ckeep[gid] = cv;        // c entering the kept iteration
  if (snap) csnap[gid] = cv;

  float p0 = 0.f, p1 = 0.f, p2 = 0.f, p3 = 0.f, p4 = 0.f, p5 = 0.f,
        p6 = 0.f, p7 = 0.f;
  float4 cnv;
#pragma unroll
  for (int e = 0; e < 4; ++e) {
    const int s = gid * 4 + e;
    const int tt = (((s & 1023) ^ 512) << 10) | (s >> 10);
    const float freq = (float)tt * (1.0f / 1048576.0f) - 0.5f;
    const float Ee = (e == 0) ? Ev.x : (e == 1) ? Ev.y : (e == 2) ? Ev.z : Ev.w;
    const float ce = (e == 0) ? cv.x : (e == 1) ? cv.y : (e == 2) ? cv.z : cv.w;
    float a0 = freq - om0, a1 = freq - om1, a2 = freq - om2;
    float d0 = a0 * a0, d1 = a1 * a1, d2 = a2 * a2;
    float w0 = 1.0f / (1.0f + ALPHA_F * (d0 + d1 + TAU2));
    float w1 = 1.0f / (1.0f + ALPHA_F * (d0 + d1 + d2 + TAU2));
    float w2 = 1.0f / (1.0f + ALPHA_F * (d1 + d2 + TAU2));
    float hfac = 1.0f - 0.5f * ce;
    float g = Ee * hfac * hfac;
    float gw0 = g * w0 * w0, gw1 = g * w1 * w1, gw2 = g * w2 * w2;
    p0 += freq * gw0; p1 += freq * gw1; p2 += freq * gw2;
    p3 += gw0;        p4 += gw1;        p5 += gw2;
    float S = w0 + w1 + w2;
    float cn = ce + TAU_F * (S * hfac - 1.0f);
    if (e == 0) cnv.x = cn; else if (e == 1) cnv.y = cn;
    else if (e == 2) cnv.z = cn; else cnv.w = cn;
    if (checkcomp) {
      const float cse = (e == 0) ? csv.x : (e == 1) ? csv.y : (e == 2) ? csv.z : csv.w;
      float hp = 1.0f - 0.5f * cse;
      float b0 = freq - pm0, b1 = freq - pm1, b2 = freq - pm2;
      float e0 = b0 * b0, e1 = b1 * b1, e2 = b2 * b2;
      float v0 = 1.0f / (1.0f + ALPHA_F * (e0 + e1 + TAU2));
      float v1 = 1.0f / (1.0f + ALPHA_F * (e0 + e1 + e2 + TAU2));
      float v2 = 1.0f / (1.0f + ALPHA_F * (e1 + e2 + TAU2));
      float q0 = hfac * w0 - hp * v0;
      float q1 = hfac * w1 - hp * v1;
      float q2 = hfac * w2 - hp * v2;
      p6 += Ee * (q0 * q0 + q1 * q1 + q2 * q2);
      p7 += Ee * (hp * hp) * (v0 * v0 + v1 * v1 + v2 * v2);
    }
  }
  c4[gid] = cnv;

  // block reduce: wave shuffle (f64) -> LDS -> per-block partial store
  {
    double pv[8] = { (double)p0, (double)p1, (double)p2, (double)p3,
                     (double)p4, (double)p5, (double)p6, (double)p7 };
    const int lane = tid & 63, wv = tid >> 6;   // 16 waves
    __syncthreads();                             // red reuse after input-reduce
#pragma unroll
    for (int j = 0; j < 8; ++j) {
      double v = pv[j];
      for (int off = 32; off; off >>= 1) v += __shfl_down(v, off, 64);
      if (lane == 0) red[wv * 8 + j] = v;
    }
    __syncthreads();
    if (tid < 8) {
      double ssum = 0.0;
#pragma unroll
      for (int wv2 = 0; wv2 < 16; ++wv2) ssum += red[wv2 * 8 + tid];
      pout[bid * 8 + tid] = ssum;
    }
  }
}

// ---------------- inverse FFT (per mode) ----------------
__global__ __launch_bounds__(256) void k_inv_passA(
    const float2* __restrict__ fhat, const float* __restrict__ ckeep,
    const float* __restrict__ omega_final, float2* __restrict__ ws0, int mode)
{
  __shared__ float Ar[PADN], Ai[PADN], Br[PADN], Bi[PADN];
  __shared__ float som[3];
  const int tid = threadIdx.x;
  if (tid == 0) { som[0] = omega_final[0]; som[1] = omega_final[1]; som[2] = omega_final[2]; }
  __syncthreads();
  const float om0 = som[0], om1 = som[1], om2 = som[2];
  const int b = swz(blockIdx.x);   // n2
  const float TAU2 = TAU_F * TAU_F;
#pragma unroll
  for (int q = 0; q < 4; ++q) {
    int j = tid + 256 * q;         // n1 ; ifftshift cancels: contiguous load
    float2 f = fhat[(size_t)b * 1024 + j];
    float ck = ckeep[(size_t)b * 1024 + j];
    float hf = 1.0f - 0.5f * ck;
    int tt = ((j ^ 512) << 10) | b;
    float freq = (float)tt * (1.0f / 1048576.0f) - 0.5f;
    float a0 = freq - om0, a1 = freq - om1, a2 = freq - om2;
    float d0 = a0 * a0, d1 = a1 * a1, d2 = a2 * a2;
    float den = (mode == 0) ? (d0 + d1) : (mode == 1) ? (d0 + d1 + d2) : (d1 + d2);
    float wk = hf / (1.0f + ALPHA_F * (den + TAU2));
    Ar[lpad(j)] = f.x * wk; Ai[lpad(j)] = f.y * wk;
  }
  __syncthreads();
  fft1024<1>(Ar, Ai, Br, Bi);
#pragma unroll
  for (int q = 0; q < 4; ++q) {
    int m1 = tid + 256 * q;
    int ph = b * m1;
    float s, c;
    sincospif((float)ph * (2.0f / 1048576.0f), &s, &c);
    float vr = Br[lpad(m1)], vi = Bi[lpad(m1)];
    ws0[(size_t)b * 1024 + m1] = make_float2(vr * c - vi * s, vi * c + vr * s);
  }
}

__global__ __launch_bounds__(256) void k_inv_passB(const float2* __restrict__ ws0,
                                                   float* __restrict__ out)
{
  __shared__ float Ar[PADN], Ai[PADN], Br[PADN], Bi[PADN];
  const int b = swz(blockIdx.x);   // m1
  const int tid = threadIdx.x;
#pragma unroll
  for (int q = 0; q < 4; ++q) {
    int j = tid + 256 * q;         // n2
    float2 v = ws0[(size_t)j * 1024 + b];
    Ar[lpad(j)] = v.x; Ai[lpad(j)] = v.y;
  }
  __syncthreads();
  fft1024<1>(Ar, Ai, Br, Bi);
#pragma unroll
  for (int q = 0; q < 4; ++q) {
    int m2 = tid + 256 * q;
    out[(size_t)m2 * 1024 + b] = Br[lpad(m2)] * (1.0f / 1048576.0f);
  }
}

// ---------------- host launch ----------------
extern "C" void kernel_launch(void* const* d_in, const int* in_sizes, int n_in,
                              void* d_out, int out_size, void* d_ws, size_t ws_size,
                              hipStream_t stream)
{
  (void)in_sizes; (void)n_in; (void)out_size; (void)ws_size;
  const float* x       = (const float*)d_in[0];
  const float* om_init = (const float*)d_in[1];
  float* out = (float*)d_out;

  char* w = (char*)d_ws;
  const size_t MB = 1024ull * 1024ull;
  float2* fhat    = (float2*)(w);
  float*  E       = (float*)(w + 8 * MB);
  float*  c       = (float*)(w + 12 * MB);
  float*  csnap   = (float*)(w + 16 * MB);
  float*  ckeep   = (float*)(w + 20 * MB);
  float2* scratch = (float2*)(w + 24 * MB);
  double* P0      = (double*)(w + 32 * MB);            // 2048 doubles
  double* P1      = (double*)(w + 32 * MB + 16 * 1024);
  float*  omhist  = (float*)(w + 32 * MB + 32 * 1024); // 200 floats
  float*  omegaF  = (float*)(w + 32 * MB + 36 * 1024);
  int*    done    = (int*)(w + 32 * MB + 40 * 1024);

  k_fwd_passA<<<1024, 256, 0, stream>>>(x, scratch);
  k_fwd_passB<<<1024, 256, 0, stream>>>(scratch, fhat, E);

  for (int n = 0; n < 50; ++n) {
    double* pin  = (n & 1) ? P0 : P1;
    double* pout = (n & 1) ? P1 : P0;
    k_iter<<<256, 1024, 0, stream>>>((const float4*)E, (float4*)c,
                                     (float4*)csnap, (float4*)ckeep,
                                     pin, pout, omhist, omegaF, done,
                                     om_init, n);
  }

  for (int mode = 0; mode < 3; ++mode) {
    k_inv_passA<<<1024, 256, 0, stream>>>(fhat, ckeep, omegaF, scratch, mode);
    k_inv_passB<<<1024, 256, 0, stream>>>(scratch, out + (size_t)mode * 1048576ull);
  }
}

// Round 6
// 437.919 us; speedup vs baseline: 4.0735x; 1.4983x over previous
//
#include <hip/hip_runtime.h>
#include <math.h>

// VMD: T = 2^20, K = 3, 50 iterations.
// Round-6 structure: spectral-moment compression.
//   - lam(t) = c(freq_t)*f_hat(t), c real & smooth in freq (round-5 algebra).
//   - All omega/convergence sums = sum_t E(t)*G(freq_t; omega, c) with G smooth
//     (min feature width sqrt(1/ALPHA)=0.0224). Partition freq into 1024 bins
//     (tt high bits = s-layout column), cubic Lagrange nodes (4/bin, h=3.26e-4,
//     interp err ~(h/w)^4 ~ 5e-8 rel). W[b][i] = sum_{t in b} E(t)*L_i(x_t)
//     exact f64. Then one iteration = 4096 node evals -> the whole 50-iter
//     loop runs in ONE workgroup (thread t = bin t, c in registers).
// Workspace (~40 MB of ~256 MB):
//   [0,8MB)   f_hat (float2, s-layout: s = k1*1024+k2, t(s) = ((k2^512)<<10)|k1)
//   [8,12MB)  E = |f_hat|^2 (float, s-layout)
//   [12MB..)  W f64[1024*4]; ckeepN float[4096]; omegaF float[4]
//   [16,40MB) scratch3 (3 x 8MB float2) -- inverse FFT intermediates

#define ALPHA_F 2000.0f
#define TAU_F   1e-7f

static __device__ __forceinline__ int lpad(int i) { return i + (i >> 5); }
static __device__ __forceinline__ int swz(int i)  { return ((i & 7) << 7) | (i >> 3); }

#define PADN 1057

// ---------------- 1024-point radix-4 Stockham FFT in LDS ----------------
template<int SIGN>   // -1 = forward (e^{-i}), +1 = inverse (e^{+i}, unscaled)
static __device__ void fft1024(float* Ar, float* Ai, float* Br, float* Bi)
{
  const int u = threadIdx.x;
#pragma unroll
  for (int st = 0; st < 5; ++st) {
    float *ir, *ii, *pr, *pi;
    if (st & 1) { ir = Br; ii = Bi; pr = Ar; pi = Ai; }
    else        { ir = Ar; ii = Ai; pr = Br; pi = Bi; }
    const int quarter = 1 << (2 * st);
    const int p = u & (quarter - 1);
    const int g = u >> (2 * st);

    float sw, cw;
    sincospif((float)(2 * p) * (1.0f / (float)(4 << (2 * st))), &sw, &cw);
    const float w1r = cw,                 w1i = (SIGN < 0) ? -sw : sw;
    const float w2r = w1r*w1r - w1i*w1i,  w2i = 2.0f*w1r*w1i;
    const float w3r = w2r*w1r - w2i*w1i,  w3i = w2r*w1i + w2i*w1r;

    float x0r = ir[lpad(u      )], x0i = ii[lpad(u      )];
    float x1r = ir[lpad(u + 256)], x1i = ii[lpad(u + 256)];
    float x2r = ir[lpad(u + 512)], x2i = ii[lpad(u + 512)];
    float x3r = ir[lpad(u + 768)], x3i = ii[lpad(u + 768)];

    float y1r = x1r*w1r - x1i*w1i, y1i = x1r*w1i + x1i*w1r;
    float y2r = x2r*w2r - x2i*w2i, y2i = x2r*w2i + x2i*w2r;
    float y3r = x3r*w3r - x3i*w3i, y3i = x3r*w3i + x3i*w3r;

    float t0r = x0r + y2r, t0i = x0i + y2i;
    float t1r = x0r - y2r, t1i = x0i - y2i;
    float t2r = y1r + y3r, t2i = y1i + y3i;
    float t3r = y1r - y3r, t3i = y1i - y3i;

    float o0r = t0r + t2r, o0i = t0i + t2i;
    float o2r = t0r - t2r, o2i = t0i - t2i;
    float o1r, o1i, o3r, o3i;
    if (SIGN < 0) {
      o1r = t1r + t3i; o1i = t1i - t3r;
      o3r = t1r - t3i; o3i = t1i + t3r;
    } else {
      o1r = t1r - t3i; o1i = t1i + t3r;
      o3r = t1r + t3i; o3i = t1i - t3r;
    }
    const int base = (g << (2 * st + 2)) + p;
    pr[lpad(base              )] = o0r; pi[lpad(base              )] = o0i;
    pr[lpad(base +     quarter)] = o1r; pi[lpad(base +     quarter)] = o1i;
    pr[lpad(base + 2 * quarter)] = o2r; pi[lpad(base + 2 * quarter)] = o2i;
    pr[lpad(base + 3 * quarter)] = o3r; pi[lpad(base + 3 * quarter)] = o3i;
    __syncthreads();
  }
}

// ---------------- forward FFT ----------------
__global__ __launch_bounds__(256) void k_fwd_passA(const float* __restrict__ x,
                                                   float2* __restrict__ ws0)
{
  __shared__ float Ar[PADN], Ai[PADN], Br[PADN], Bi[PADN];
  const int b = swz(blockIdx.x);   // n2
  const int tid = threadIdx.x;
#pragma unroll
  for (int q = 0; q < 4; ++q) {
    int j = tid + 256 * q;         // n1
    Ar[lpad(j)] = x[(size_t)j * 1024 + b];
    Ai[lpad(j)] = 0.0f;
  }
  __syncthreads();
  fft1024<-1>(Ar, Ai, Br, Bi);
#pragma unroll
  for (int q = 0; q < 4; ++q) {
    int k1 = tid + 256 * q;
    int ph = b * k1;               // < 2^20, exact in fp32
    float s, c;
    sincospif((float)ph * (2.0f / 1048576.0f), &s, &c);
    float vr = Br[lpad(k1)], vi = Bi[lpad(k1)];
    ws0[(size_t)b * 1024 + k1] = make_float2(vr * c + vi * s, vi * c - vr * s);
  }
}

__global__ __launch_bounds__(256) void k_fwd_passB(const float2* __restrict__ ws0,
                                                   float2* __restrict__ fhat,
                                                   float* __restrict__ E)
{
  __shared__ float Ar[PADN], Ai[PADN], Br[PADN], Bi[PADN];
  const int b = swz(blockIdx.x);   // k1
  const int tid = threadIdx.x;
#pragma unroll
  for (int q = 0; q < 4; ++q) {
    int j = tid + 256 * q;         // n2
    float2 v = ws0[(size_t)j * 1024 + b];
    Ar[lpad(j)] = v.x; Ai[lpad(j)] = v.y;
  }
  __syncthreads();
  fft1024<-1>(Ar, Ai, Br, Bi);
#pragma unroll
  for (int q = 0; q < 4; ++q) {
    int k2 = tid + 256 * q;
    float vr = Br[lpad(k2)], vi = Bi[lpad(k2)];
    fhat[(size_t)b * 1024 + k2] = make_float2(vr, vi);
    E[(size_t)b * 1024 + k2] = vr * vr + vi * vi;
  }
}

// ---------------- Lagrange basis on nodes x = {0, 1/3, 2/3, 1} --------------
static __device__ __forceinline__ void lag4(float x, float& l0, float& l1,
                                            float& l2, float& l3)
{
  float m0 = x, m1 = x - (1.0f / 3.0f), m2 = x - (2.0f / 3.0f), m3 = x - 1.0f;
  l0 = -4.5f * m1 * m2 * m3;
  l1 = 13.5f * m0 * m2 * m3;
  l2 = -13.5f * m0 * m1 * m3;
  l3 =  4.5f * m0 * m1 * m2;
}

// ---------------- bin weights: W[b][i] = sum_{t in bin b} E(t) L_i(x_t) -----
// bin b = tt>>10 = (s&1023)^512 ; x = (s>>10)/1024. One block per bin.
__global__ __launch_bounds__(256) void k_moments(const float* __restrict__ E,
                                                 double* __restrict__ W)
{
  __shared__ double red[4 * 4];
  const int B = blockIdx.x;
  const int k2 = B ^ 512;
  const int tid = threadIdx.x;
  double a0 = 0, a1 = 0, a2 = 0, a3 = 0;
#pragma unroll
  for (int q = 0; q < 4; ++q) {
    int k1 = tid + 256 * q;
    float e = E[(size_t)k1 * 1024 + k2];
    float l0, l1, l2, l3;
    lag4((float)k1 * (1.0f / 1024.0f), l0, l1, l2, l3);
    a0 += (double)(e * l0); a1 += (double)(e * l1);
    a2 += (double)(e * l2); a3 += (double)(e * l3);
  }
  const int lane = tid & 63, wv = tid >> 6;       // 4 waves
  double pv[4] = { a0, a1, a2, a3 };
#pragma unroll
  for (int j = 0; j < 4; ++j) {
    double v = pv[j];
    for (int off = 32; off; off >>= 1) v += __shfl_down(v, off, 64);
    if (lane == 0) red[wv * 4 + j] = v;
  }
  __syncthreads();
  if (tid < 4)
    W[B * 4 + tid] = red[tid] + red[4 + tid] + red[8 + tid] + red[12 + tid];
}

// ---------------- the whole 50-iteration loop in ONE workgroup --------------
// thread t = bin t ; 4 cubic nodes per bin; c, csnap, W in registers.
__global__ __launch_bounds__(1024) void k_solve(
    const double* __restrict__ W4, const float* __restrict__ omega_init,
    float* __restrict__ ckeepN, float* __restrict__ omegaF)
{
  __shared__ double red[16 * 8];
  __shared__ double sbd[8];
  const int t = threadIdx.x;

  double Wr[4]; float fr[4], cnr[4], csr[4];
#pragma unroll
  for (int e = 0; e < 4; ++e) {
    Wr[e] = W4[t * 4 + e];
    fr[e] = (float)((double)t / 1024.0 + (double)e / 3072.0 - 0.5);
    cnr[e] = 0.0f; csr[e] = 0.0f;
  }
  float om0 = omega_init[0], om1 = omega_init[1], om2 = omega_init[2];
  float pm0 = 0.f, pm1 = 0.f, pm2 = 0.f;
  const float TAU2 = TAU_F * TAU_F;

#pragma unroll 1
  for (int n = 0; n < 50; ++n) {
    const bool snap  = (n == 9) || (n == 19) || (n == 29) || (n == 39);
    const bool check = (n == 10) || (n == 20) || (n == 30) || (n == 40);
    const bool keep  = check || (n == 49);

    if (snap) {
#pragma unroll
      for (int e = 0; e < 4; ++e) csr[e] = cnr[e];
      pm0 = om0; pm1 = om1; pm2 = om2;
    }
    if (keep) {                                   // entry state of this iter
      ((float4*)ckeepN)[t] = make_float4(cnr[0], cnr[1], cnr[2], cnr[3]);
      if (t == 0) { omegaF[0] = om0; omegaF[1] = om1; omegaF[2] = om2; }
    }

    double p0 = 0, p1 = 0, p2 = 0, p3 = 0, p4 = 0, p5 = 0, p6 = 0, p7 = 0;
#pragma unroll
    for (int e = 0; e < 4; ++e) {
      const float f = fr[e];
      float a0 = f - om0, a1 = f - om1, a2 = f - om2;
      float d0 = a0 * a0, d1 = a1 * a1, d2 = a2 * a2;
      float w0 = 1.0f / (1.0f + ALPHA_F * (d0 + d1 + TAU2));
      float w1 = 1.0f / (1.0f + ALPHA_F * (d0 + d1 + d2 + TAU2));
      float w2 = 1.0f / (1.0f + ALPHA_F * (d1 + d2 + TAU2));
      float hf = 1.0f - 0.5f * cnr[e];
      float g = hf * hf;
      float gw0 = g * w0 * w0, gw1 = g * w1 * w1, gw2 = g * w2 * w2;
      const double wj = Wr[e];
      p0 += wj * (double)(f * gw0); p1 += wj * (double)(f * gw1);
      p2 += wj * (double)(f * gw2);
      p3 += wj * (double)gw0; p4 += wj * (double)gw1; p5 += wj * (double)gw2;
      float S = w0 + w1 + w2;
      cnr[e] += TAU_F * (S * hf - 1.0f);
      if (check) {
        float hp = 1.0f - 0.5f * csr[e];
        float b0 = f - pm0, b1 = f - pm1, b2 = f - pm2;
        float e0 = b0 * b0, e1 = b1 * b1, e2 = b2 * b2;
        float v0 = 1.0f / (1.0f + ALPHA_F * (e0 + e1 + TAU2));
        float v1 = 1.0f / (1.0f + ALPHA_F * (e0 + e1 + e2 + TAU2));
        float v2 = 1.0f / (1.0f + ALPHA_F * (e1 + e2 + TAU2));
        float q0 = hf * w0 - hp * v0;
        float q1 = hf * w1 - hp * v1;
        float q2 = hf * w2 - hp * v2;
        p6 += wj * (double)(q0 * q0 + q1 * q1 + q2 * q2);
        p7 += wj * (double)((hp * hp) * (v0 * v0 + v1 * v1 + v2 * v2));
      }
    }

    // block reduce 8 f64 sums (16 waves)
    {
      double pv[8] = { p0, p1, p2, p3, p4, p5, p6, p7 };
      const int lane = t & 63, wv = t >> 6;
#pragma unroll
      for (int j = 0; j < 8; ++j) {
        double v = pv[j];
        for (int off = 32; off; off >>= 1) v += __shfl_down(v, off, 64);
        if (lane == 0) red[wv * 8 + j] = v;
      }
    }
    __syncthreads();
    if (t < 8) {
      double s = 0.0;
#pragma unroll
      for (int wv = 0; wv < 16; ++wv) s += red[wv * 8 + t];
      sbd[t] = s;
    }
    __syncthreads();
    float no0 = (float)(sbd[0] / sbd[3]);
    float no1 = (float)(sbd[1] / sbd[4]);
    float no2 = (float)(sbd[2] / sbd[5]);
    bool conv = false;
    if (check) {
      bool ud_ok = sbd[6] < 1e-6 * sbd[7];
      float omd = (fabsf(no0 - no2) + fabsf(no1 - no0) + fabsf(no2 - no1))
                  * (1.0f / 3.0f);
      conv = ud_ok && (omd < 1e-6f);
    }
    om0 = no0; om1 = no1; om2 = no2;
    __syncthreads();                 // protect red/sbd reuse next iteration
    if (conv) break;                 // uniform: same sbd in every thread
  }
}

// ---------------- fused inverse passA (all 3 modes) ----------------
__global__ __launch_bounds__(256) void k_inv_A3(
    const float2* __restrict__ fhat, const float* __restrict__ ckeepN,
    const float* __restrict__ omegaF, float2* __restrict__ ws0)
{
  __shared__ float Ar[PADN], Ai[PADN], Br[PADN], Bi[PADN];
  __shared__ float cn4[4096];
  __shared__ float som[3];
  const int tid = threadIdx.x;
  const int b = swz(blockIdx.x);   // k1 of s-layout (x-position of this block)
  for (int i = tid; i < 4096; i += 256) cn4[i] = ckeepN[i];
  if (tid == 0) { som[0] = omegaF[0]; som[1] = omegaF[1]; som[2] = omegaF[2]; }
  __syncthreads();
  const float om0 = som[0], om1 = som[1], om2 = som[2];
  const float TAU2 = TAU_F * TAU_F;
  float l0, l1, l2, l3;
  lag4((float)b * (1.0f / 1024.0f), l0, l1, l2, l3);

#pragma unroll 1
  for (int mode = 0; mode < 3; ++mode) {
#pragma unroll
    for (int q = 0; q < 4; ++q) {
      int j = tid + 256 * q;       // k2 ; bin = j^512, x = b/1024 (block-fixed)
      float2 f = fhat[(size_t)b * 1024 + j];
      int bin = j ^ 512;
      float4 cv = ((const float4*)cn4)[bin];
      float c = l0 * cv.x + l1 * cv.y + l2 * cv.z + l3 * cv.w;
      float hf = 1.0f - 0.5f * c;
      int tt = (bin << 10) | b;
      float freq = (float)tt * (1.0f / 1048576.0f) - 0.5f;
      float a0 = freq - om0, a1 = freq - om1, a2 = freq - om2;
      float d0 = a0 * a0, d1 = a1 * a1, d2 = a2 * a2;
      float den = (mode == 0) ? (d0 + d1) : (mode == 1) ? (d0 + d1 + d2)
                                                        : (d1 + d2);
      float wk = hf / (1.0f + ALPHA_F * (den + TAU2));
      Ar[lpad(j)] = f.x * wk; Ai[lpad(j)] = f.y * wk;
    }
    __syncthreads();
    fft1024<1>(Ar, Ai, Br, Bi);
#pragma unroll
    for (int q = 0; q < 4; ++q) {
      int m1 = tid + 256 * q;
      int ph = b * m1;
      float s, c;
      sincospif((float)ph * (2.0f / 1048576.0f), &s, &c);
      float vr = Br[lpad(m1)], vi = Bi[lpad(m1)];
      ws0[(size_t)mode * 1048576 + (size_t)b * 1024 + m1]
          = make_float2(vr * c - vi * s, vi * c + vr * s);
    }
    __syncthreads();
  }
}

// ---------------- fused inverse passB (all 3 modes) ----------------
__global__ __launch_bounds__(256) void k_inv_B3(const float2* __restrict__ ws0,
                                                float* __restrict__ out)
{
  __shared__ float Ar[PADN], Ai[PADN], Br[PADN], Bi[PADN];
  const int b = swz(blockIdx.x);   // m1
  const int tid = threadIdx.x;
#pragma unroll 1
  for (int mode = 0; mode < 3; ++mode) {
#pragma unroll
    for (int q = 0; q < 4; ++q) {
      int j = tid + 256 * q;       // n2
      float2 v = ws0[(size_t)mode * 1048576 + (size_t)j * 1024 + b];
      Ar[lpad(j)] = v.x; Ai[lpad(j)] = v.y;
    }
    __syncthreads();
    fft1024<1>(Ar, Ai, Br, Bi);
#pragma unroll
    for (int q = 0; q < 4; ++q) {
      int m2 = tid + 256 * q;
      out[(size_t)mode * 1048576 + (size_t)m2 * 1024 + b]
          = Br[lpad(m2)] * (1.0f / 1048576.0f);
    }
    __syncthreads();
  }
}

// ---------------- host launch ----------------
extern "C" void kernel_launch(void* const* d_in, const int* in_sizes, int n_in,
                              void* d_out, int out_size, void* d_ws, size_t ws_size,
                              hipStream_t stream)
{
  (void)in_sizes; (void)n_in; (void)out_size; (void)ws_size;
  const float* x       = (const float*)d_in[0];
  const float* om_init = (const float*)d_in[1];
  float* out = (float*)d_out;

  char* w = (char*)d_ws;
  const size_t MB = 1024ull * 1024ull;
  float2* fhat     = (float2*)(w);
  float*  E        = (float*)(w + 8 * MB);
  double* W4       = (double*)(w + 12 * MB);            // 4096 doubles (32 KB)
  float*  ckeepN   = (float*)(w + 12 * MB + 32 * 1024); // 4096 floats
  float*  omegaF   = (float*)(w + 12 * MB + 48 * 1024);
  float2* scratch3 = (float2*)(w + 16 * MB);            // 3 x 8 MB

  k_fwd_passA<<<1024, 256, 0, stream>>>(x, scratch3);
  k_fwd_passB<<<1024, 256, 0, stream>>>(scratch3, fhat, E);
  k_moments<<<1024, 256, 0, stream>>>(E, W4);
  k_solve<<<1, 1024, 0, stream>>>(W4, om_init, ckeepN, omegaF);
  k_inv_A3<<<1024, 256, 0, stream>>>(fhat, ckeepN, omegaF, scratch3);
  k_inv_B3<<<1024, 256, 0, stream>>>(scratch3, out);
}

// Round 7
// 275.493 us; speedup vs baseline: 6.4752x; 1.5896x over previous
//
#include <hip/hip_runtime.h>
#include <math.h>

// VMD: T = 2^20, K = 3, 50 iterations.
// Round-7: k_solve reduction rebuilt -- DPP wave-sum (VALU only, no ds_bpermute),
// all-f32 hot loop (f64 only in the 16-way cross-wave sum), 2 barriers/iter.
// Everything else identical to round 6 (437 us, absmax 1.95e-3).
// Workspace (~40 MB of ~256 MB):
//   [0,8MB)   f_hat (float2, s-layout: s = k1*1024+k2, t(s) = ((k2^512)<<10)|k1)
//   [8,12MB)  E = |f_hat|^2 (float, s-layout)
//   [12MB..)  W f64[1024*4]; ckeepN float[4096]; omegaF float[4]
//   [16,40MB) scratch3 (3 x 8MB float2) -- inverse FFT intermediates

#define ALPHA_F 2000.0f
#define TAU_F   1e-7f

static __device__ __forceinline__ int lpad(int i) { return i + (i >> 5); }
static __device__ __forceinline__ int swz(int i)  { return ((i & 7) << 7) | (i >> 3); }

#define PADN 1057

// ---------------- DPP wave-64 sum (VALU pipe only) ----------------
// old=0 + masks 0xf: invalid-source lanes contribute 0. Result in lane 63.
template<int CTRL>
static __device__ __forceinline__ float dpp_addf(float v)
{
  int r = __builtin_amdgcn_update_dpp(0, __float_as_int(v), CTRL, 0xf, 0xf, true);
  return v + __int_as_float(r);
}
static __device__ __forceinline__ float wave64_sum(float v)
{
  v = dpp_addf<0x111>(v);   // row_shr:1
  v = dpp_addf<0x112>(v);   // row_shr:2
  v = dpp_addf<0x114>(v);   // row_shr:4
  v = dpp_addf<0x118>(v);   // row_shr:8  -> lane 15 of each row = row sum
  v = dpp_addf<0x142>(v);   // row_bcast:15
  v = dpp_addf<0x143>(v);   // row_bcast:31 -> lane 63 = full sum
  return v;
}

// ---------------- 1024-point radix-4 Stockham FFT in LDS ----------------
template<int SIGN>   // -1 = forward (e^{-i}), +1 = inverse (e^{+i}, unscaled)
static __device__ void fft1024(float* Ar, float* Ai, float* Br, float* Bi)
{
  const int u = threadIdx.x;
#pragma unroll
  for (int st = 0; st < 5; ++st) {
    float *ir, *ii, *pr, *pi;
    if (st & 1) { ir = Br; ii = Bi; pr = Ar; pi = Ai; }
    else        { ir = Ar; ii = Ai; pr = Br; pi = Bi; }
    const int quarter = 1 << (2 * st);
    const int p = u & (quarter - 1);
    const int g = u >> (2 * st);

    float sw, cw;
    sincospif((float)(2 * p) * (1.0f / (float)(4 << (2 * st))), &sw, &cw);
    const float w1r = cw,                 w1i = (SIGN < 0) ? -sw : sw;
    const float w2r = w1r*w1r - w1i*w1i,  w2i = 2.0f*w1r*w1i;
    const float w3r = w2r*w1r - w2i*w1i,  w3i = w2r*w1i + w2i*w1r;

    float x0r = ir[lpad(u      )], x0i = ii[lpad(u      )];
    float x1r = ir[lpad(u + 256)], x1i = ii[lpad(u + 256)];
    float x2r = ir[lpad(u + 512)], x2i = ii[lpad(u + 512)];
    float x3r = ir[lpad(u + 768)], x3i = ii[lpad(u + 768)];

    float y1r = x1r*w1r - x1i*w1i, y1i = x1r*w1i + x1i*w1r;
    float y2r = x2r*w2r - x2i*w2i, y2i = x2r*w2i + x2i*w2r;
    float y3r = x3r*w3r - x3i*w3i, y3i = x3r*w3i + x3i*w3r;

    float t0r = x0r + y2r, t0i = x0i + y2i;
    float t1r = x0r - y2r, t1i = x0i - y2i;
    float t2r = y1r + y3r, t2i = y1i + y3i;
    float t3r = y1r - y3r, t3i = y1i - y3i;

    float o0r = t0r + t2r, o0i = t0i + t2i;
    float o2r = t0r - t2r, o2i = t0i - t2i;
    float o1r, o1i, o3r, o3i;
    if (SIGN < 0) {
      o1r = t1r + t3i; o1i = t1i - t3r;
      o3r = t1r - t3i; o3i = t1i + t3r;
    } else {
      o1r = t1r - t3i; o1i = t1i + t3r;
      o3r = t1r + t3i; o3i = t1i - t3r;
    }
    const int base = (g << (2 * st + 2)) + p;
    pr[lpad(base              )] = o0r; pi[lpad(base              )] = o0i;
    pr[lpad(base +     quarter)] = o1r; pi[lpad(base +     quarter)] = o1i;
    pr[lpad(base + 2 * quarter)] = o2r; pi[lpad(base + 2 * quarter)] = o2i;
    pr[lpad(base + 3 * quarter)] = o3r; pi[lpad(base + 3 * quarter)] = o3i;
    __syncthreads();
  }
}

// ---------------- forward FFT ----------------
__global__ __launch_bounds__(256) void k_fwd_passA(const float* __restrict__ x,
                                                   float2* __restrict__ ws0)
{
  __shared__ float Ar[PADN], Ai[PADN], Br[PADN], Bi[PADN];
  const int b = swz(blockIdx.x);   // n2
  const int tid = threadIdx.x;
#pragma unroll
  for (int q = 0; q < 4; ++q) {
    int j = tid + 256 * q;         // n1
    Ar[lpad(j)] = x[(size_t)j * 1024 + b];
    Ai[lpad(j)] = 0.0f;
  }
  __syncthreads();
  fft1024<-1>(Ar, Ai, Br, Bi);
#pragma unroll
  for (int q = 0; q < 4; ++q) {
    int k1 = tid + 256 * q;
    int ph = b * k1;               // < 2^20, exact in fp32
    float s, c;
    sincospif((float)ph * (2.0f / 1048576.0f), &s, &c);
    float vr = Br[lpad(k1)], vi = Bi[lpad(k1)];
    ws0[(size_t)b * 1024 + k1] = make_float2(vr * c + vi * s, vi * c - vr * s);
  }
}

__global__ __launch_bounds__(256) void k_fwd_passB(const float2* __restrict__ ws0,
                                                   float2* __restrict__ fhat,
                                                   float* __restrict__ E)
{
  __shared__ float Ar[PADN], Ai[PADN], Br[PADN], Bi[PADN];
  const int b = swz(blockIdx.x);   // k1
  const int tid = threadIdx.x;
#pragma unroll
  for (int q = 0; q < 4; ++q) {
    int j = tid + 256 * q;         // n2
    float2 v = ws0[(size_t)j * 1024 + b];
    Ar[lpad(j)] = v.x; Ai[lpad(j)] = v.y;
  }
  __syncthreads();
  fft1024<-1>(Ar, Ai, Br, Bi);
#pragma unroll
  for (int q = 0; q < 4; ++q) {
    int k2 = tid + 256 * q;
    float vr = Br[lpad(k2)], vi = Bi[lpad(k2)];
    fhat[(size_t)b * 1024 + k2] = make_float2(vr, vi);
    E[(size_t)b * 1024 + k2] = vr * vr + vi * vi;
  }
}

// ---------------- Lagrange basis on nodes x = {0, 1/3, 2/3, 1} --------------
static __device__ __forceinline__ void lag4(float x, float& l0, float& l1,
                                            float& l2, float& l3)
{
  float m0 = x, m1 = x - (1.0f / 3.0f), m2 = x - (2.0f / 3.0f), m3 = x - 1.0f;
  l0 = -4.5f * m1 * m2 * m3;
  l1 = 13.5f * m0 * m2 * m3;
  l2 = -13.5f * m0 * m1 * m3;
  l3 =  4.5f * m0 * m1 * m2;
}

// ---------------- bin weights: W[b][i] = sum_{t in bin b} E(t) L_i(x_t) -----
__global__ __launch_bounds__(256) void k_moments(const float* __restrict__ E,
                                                 double* __restrict__ W)
{
  __shared__ double red[4 * 4];
  const int B = blockIdx.x;
  const int k2 = B ^ 512;
  const int tid = threadIdx.x;
  double a0 = 0, a1 = 0, a2 = 0, a3 = 0;
#pragma unroll
  for (int q = 0; q < 4; ++q) {
    int k1 = tid + 256 * q;
    float e = E[(size_t)k1 * 1024 + k2];
    float l0, l1, l2, l3;
    lag4((float)k1 * (1.0f / 1024.0f), l0, l1, l2, l3);
    a0 += (double)(e * l0); a1 += (double)(e * l1);
    a2 += (double)(e * l2); a3 += (double)(e * l3);
  }
  const int lane = tid & 63, wv = tid >> 6;       // 4 waves
  double pv[4] = { a0, a1, a2, a3 };
#pragma unroll
  for (int j = 0; j < 4; ++j) {
    double v = pv[j];
    for (int off = 32; off; off >>= 1) v += __shfl_down(v, off, 64);
    if (lane == 0) red[wv * 4 + j] = v;
  }
  __syncthreads();
  if (tid < 4)
    W[B * 4 + tid] = red[tid] + red[4 + tid] + red[8 + tid] + red[12 + tid];
}

// ---------------- the whole 50-iteration loop in ONE workgroup --------------
// thread t = bin t ; 4 cubic nodes/bin; W, c, csnap in registers; DPP reduce.
__global__ __launch_bounds__(1024) void k_solve(
    const double* __restrict__ W4, const float* __restrict__ omega_init,
    float* __restrict__ ckeepN, float* __restrict__ omegaF)
{
  __shared__ float red[16 * 8];
  __shared__ double sbd[8];
  const int t = threadIdx.x;
  const int lane = t & 63, wv = t >> 6;

  float Wr[4], fr[4], cnr[4], csr[4];
#pragma unroll
  for (int e = 0; e < 4; ++e) {
    Wr[e] = (float)W4[t * 4 + e];
    fr[e] = (float)((double)t / 1024.0 + (double)e / 3072.0 - 0.5);
    cnr[e] = 0.0f; csr[e] = 0.0f;
  }
  float om0 = omega_init[0], om1 = omega_init[1], om2 = omega_init[2];
  float pm0 = 0.f, pm1 = 0.f, pm2 = 0.f;
  const float TAU2 = TAU_F * TAU_F;

#pragma unroll 1
  for (int n = 0; n < 50; ++n) {
    const bool snap  = (n == 9) || (n == 19) || (n == 29) || (n == 39);
    const bool check = (n == 10) || (n == 20) || (n == 30) || (n == 40);
    const bool keep  = check || (n == 49);

    if (snap) {
#pragma unroll
      for (int e = 0; e < 4; ++e) csr[e] = cnr[e];
      pm0 = om0; pm1 = om1; pm2 = om2;
    }
    if (keep) {                                   // entry state of this iter
      ((float4*)ckeepN)[t] = make_float4(cnr[0], cnr[1], cnr[2], cnr[3]);
      if (t == 0) { omegaF[0] = om0; omegaF[1] = om1; omegaF[2] = om2; }
    }

    float p0 = 0.f, p1 = 0.f, p2 = 0.f, p3 = 0.f, p4 = 0.f, p5 = 0.f,
          p6 = 0.f, p7 = 0.f;
#pragma unroll
    for (int e = 0; e < 4; ++e) {
      const float f = fr[e];
      float a0 = f - om0, a1 = f - om1, a2 = f - om2;
      float d0 = a0 * a0, d1 = a1 * a1, d2 = a2 * a2;
      float w0 = 1.0f / (1.0f + ALPHA_F * (d0 + d1 + TAU2));
      float w1 = 1.0f / (1.0f + ALPHA_F * (d0 + d1 + d2 + TAU2));
      float w2 = 1.0f / (1.0f + ALPHA_F * (d1 + d2 + TAU2));
      float hf = 1.0f - 0.5f * cnr[e];
      float g = hf * hf;
      float gw0 = g * w0 * w0, gw1 = g * w1 * w1, gw2 = g * w2 * w2;
      const float wj = Wr[e];
      p0 += wj * (f * gw0); p1 += wj * (f * gw1); p2 += wj * (f * gw2);
      p3 += wj * gw0;       p4 += wj * gw1;       p5 += wj * gw2;
      float S = w0 + w1 + w2;
      cnr[e] += TAU_F * (S * hf - 1.0f);
      if (check) {
        float hp = 1.0f - 0.5f * csr[e];
        float b0 = f - pm0, b1 = f - pm1, b2 = f - pm2;
        float e0 = b0 * b0, e1 = b1 * b1, e2 = b2 * b2;
        float v0 = 1.0f / (1.0f + ALPHA_F * (e0 + e1 + TAU2));
        float v1 = 1.0f / (1.0f + ALPHA_F * (e0 + e1 + e2 + TAU2));
        float v2 = 1.0f / (1.0f + ALPHA_F * (e1 + e2 + TAU2));
        float q0 = hf * w0 - hp * v0;
        float q1 = hf * w1 - hp * v1;
        float q2 = hf * w2 - hp * v2;
        p6 += wj * (q0 * q0 + q1 * q1 + q2 * q2);
        p7 += wj * ((hp * hp) * (v0 * v0 + v1 * v1 + v2 * v2));
      }
    }

    // DPP wave reduce (VALU only); full sums land in lane 63
    p0 = wave64_sum(p0); p1 = wave64_sum(p1); p2 = wave64_sum(p2);
    p3 = wave64_sum(p3); p4 = wave64_sum(p4); p5 = wave64_sum(p5);
    if (check) { p6 = wave64_sum(p6); p7 = wave64_sum(p7); }
    if (lane == 63) {
      red[wv * 8 + 0] = p0; red[wv * 8 + 1] = p1; red[wv * 8 + 2] = p2;
      red[wv * 8 + 3] = p3; red[wv * 8 + 4] = p4; red[wv * 8 + 5] = p5;
      red[wv * 8 + 6] = p6; red[wv * 8 + 7] = p7;
    }
    __syncthreads();
    if (t < 8) {
      double s = 0.0;
#pragma unroll
      for (int w2 = 0; w2 < 16; ++w2) s += (double)red[w2 * 8 + t];
      sbd[t] = s;
    }
    __syncthreads();
    float no0 = (float)(sbd[0] / sbd[3]);
    float no1 = (float)(sbd[1] / sbd[4]);
    float no2 = (float)(sbd[2] / sbd[5]);
    bool conv = false;
    if (check) {
      bool ud_ok = sbd[6] < 1e-6 * sbd[7];
      float omd = (fabsf(no0 - no2) + fabsf(no1 - no0) + fabsf(no2 - no1))
                  * (1.0f / 3.0f);
      conv = ud_ok && (omd < 1e-6f);
    }
    om0 = no0; om1 = no1; om2 = no2;
    // barrier1 of iter n+1 orders this iter's sbd reads before the next writes
    if (conv) break;                 // uniform: same sbd in every thread
  }
}

// ---------------- fused inverse passA (all 3 modes) ----------------
__global__ __launch_bounds__(256) void k_inv_A3(
    const float2* __restrict__ fhat, const float* __restrict__ ckeepN,
    const float* __restrict__ omegaF, float2* __restrict__ ws0)
{
  __shared__ float Ar[PADN], Ai[PADN], Br[PADN], Bi[PADN];
  __shared__ float cn4[4096];
  __shared__ float som[3];
  const int tid = threadIdx.x;
  const int b = swz(blockIdx.x);   // k1 of s-layout (x-position of this block)
  for (int i = tid; i < 4096; i += 256) cn4[i] = ckeepN[i];
  if (tid == 0) { som[0] = omegaF[0]; som[1] = omegaF[1]; som[2] = omegaF[2]; }
  __syncthreads();
  const float om0 = som[0], om1 = som[1], om2 = som[2];
  const float TAU2 = TAU_F * TAU_F;
  float l0, l1, l2, l3;
  lag4((float)b * (1.0f / 1024.0f), l0, l1, l2, l3);

#pragma unroll 1
  for (int mode = 0; mode < 3; ++mode) {
#pragma unroll
    for (int q = 0; q < 4; ++q) {
      int j = tid + 256 * q;       // k2 ; bin = j^512, x = b/1024 (block-fixed)
      float2 f = fhat[(size_t)b * 1024 + j];
      int bin = j ^ 512;
      float4 cv = ((const float4*)cn4)[bin];
      float c = l0 * cv.x + l1 * cv.y + l2 * cv.z + l3 * cv.w;
      float hf = 1.0f - 0.5f * c;
      int tt = (bin << 10) | b;
      float freq = (float)tt * (1.0f / 1048576.0f) - 0.5f;
      float a0 = freq - om0, a1 = freq - om1, a2 = freq - om2;
      float d0 = a0 * a0, d1 = a1 * a1, d2 = a2 * a2;
      float den = (mode == 0) ? (d0 + d1) : (mode == 1) ? (d0 + d1 + d2)
                                                        : (d1 + d2);
      float wk = hf / (1.0f + ALPHA_F * (den + TAU2));
      Ar[lpad(j)] = f.x * wk; Ai[lpad(j)] = f.y * wk;
    }
    __syncthreads();
    fft1024<1>(Ar, Ai, Br, Bi);
#pragma unroll
    for (int q = 0; q < 4; ++q) {
      int m1 = tid + 256 * q;
      int ph = b * m1;
      float s, c;
      sincospif((float)ph * (2.0f / 1048576.0f), &s, &c);
      float vr = Br[lpad(m1)], vi = Bi[lpad(m1)];
      ws0[(size_t)mode * 1048576 + (size_t)b * 1024 + m1]
          = make_float2(vr * c - vi * s, vi * c + vr * s);
    }
    __syncthreads();
  }
}

// ---------------- fused inverse passB (all 3 modes) ----------------
__global__ __launch_bounds__(256) void k_inv_B3(const float2* __restrict__ ws0,
                                                float* __restrict__ out)
{
  __shared__ float Ar[PADN], Ai[PADN], Br[PADN], Bi[PADN];
  const int b = swz(blockIdx.x);   // m1
  const int tid = threadIdx.x;
#pragma unroll 1
  for (int mode = 0; mode < 3; ++mode) {
#pragma unroll
    for (int q = 0; q < 4; ++q) {
      int j = tid + 256 * q;       // n2
      float2 v = ws0[(size_t)mode * 1048576 + (size_t)j * 1024 + b];
      Ar[lpad(j)] = v.x; Ai[lpad(j)] = v.y;
    }
    __syncthreads();
    fft1024<1>(Ar, Ai, Br, Bi);
#pragma unroll
    for (int q = 0; q < 4; ++q) {
      int m2 = tid + 256 * q;
      out[(size_t)mode * 1048576 + (size_t)m2 * 1024 + b]
          = Br[lpad(m2)] * (1.0f / 1048576.0f);
    }
    __syncthreads();
  }
}

// ---------------- host launch ----------------
extern "C" void kernel_launch(void* const* d_in, const int* in_sizes, int n_in,
                              void* d_out, int out_size, void* d_ws, size_t ws_size,
                              hipStream_t stream)
{
  (void)in_sizes; (void)n_in; (void)out_size; (void)ws_size;
  const float* x       = (const float*)d_in[0];
  const float* om_init = (const float*)d_in[1];
  float* out = (float*)d_out;

  char* w = (char*)d_ws;
  const size_t MB = 1024ull * 1024ull;
  float2* fhat     = (float2*)(w);
  float*  E        = (float*)(w + 8 * MB);
  double* W4       = (double*)(w + 12 * MB);            // 4096 doubles (32 KB)
  float*  ckeepN   = (float*)(w + 12 * MB + 32 * 1024); // 4096 floats
  float*  omegaF   = (float*)(w + 12 * MB + 48 * 1024);
  float2* scratch3 = (float2*)(w + 16 * MB);            // 3 x 8 MB

  k_fwd_passA<<<1024, 256, 0, stream>>>(x, scratch3);
  k_fwd_passB<<<1024, 256, 0, stream>>>(scratch3, fhat, E);
  k_moments<<<1024, 256, 0, stream>>>(E, W4);
  k_solve<<<1, 1024, 0, stream>>>(W4, om_init, ckeepN, omegaF);
  k_inv_A3<<<1024, 256, 0, stream>>>(fhat, ckeepN, omegaF, scratch3);
  k_inv_B3<<<1024, 256, 0, stream>>>(scratch3, out);
}

// Round 8
// 234.247 us; speedup vs baseline: 7.6154x; 1.1761x over previous
//
#include <hip/hip_runtime.h>
#include <math.h>

// VMD: T = 2^20, K = 3, 50 iterations.
// Round-8: (1) k_solve uses raw v_rcp_f32 (1 inst) instead of IEEE div
// expansion (~10 insts) for all 1/(1+x) -- rel err ~1e-7, same scale as the
// f32-accumulation noise already proven harmless (absmax byte-identical
// across 3 different summation schemes in rounds 5-7).
// (2) inverse kernels split by mode (3072 blocks) -- removes serial 3x FFT
// loop per block.
// Workspace (~40 MB of ~256 MB):
//   [0,8MB)   f_hat (float2, s-layout: s = k1*1024+k2, t(s) = ((k2^512)<<10)|k1)
//   [8,12MB)  E = |f_hat|^2 (float, s-layout)
//   [12MB..)  W f64[1024*4]; ckeepN float[4096]; omegaF float[4]
//   [16,40MB) scratch3 (3 x 8MB float2) -- inverse FFT intermediates

#define ALPHA_F 2000.0f
#define TAU_F   1e-7f

static __device__ __forceinline__ int lpad(int i) { return i + (i >> 5); }
static __device__ __forceinline__ int swz(int i)  { return ((i & 7) << 7) | (i >> 3); }
static __device__ __forceinline__ float frcp(float x) { return __builtin_amdgcn_rcpf(x); }

#define PADN 1057

// ---------------- DPP wave-64 sum (VALU pipe only) ----------------
template<int CTRL>
static __device__ __forceinline__ float dpp_addf(float v)
{
  int r = __builtin_amdgcn_update_dpp(0, __float_as_int(v), CTRL, 0xf, 0xf, true);
  return v + __int_as_float(r);
}
static __device__ __forceinline__ float wave64_sum(float v)
{
  v = dpp_addf<0x111>(v);   // row_shr:1
  v = dpp_addf<0x112>(v);   // row_shr:2
  v = dpp_addf<0x114>(v);   // row_shr:4
  v = dpp_addf<0x118>(v);   // row_shr:8  -> lane 15 of each row = row sum
  v = dpp_addf<0x142>(v);   // row_bcast:15
  v = dpp_addf<0x143>(v);   // row_bcast:31 -> lane 63 = full sum
  return v;
}

// ---------------- 1024-point radix-4 Stockham FFT in LDS ----------------
template<int SIGN>   // -1 = forward (e^{-i}), +1 = inverse (e^{+i}, unscaled)
static __device__ void fft1024(float* Ar, float* Ai, float* Br, float* Bi)
{
  const int u = threadIdx.x;
#pragma unroll
  for (int st = 0; st < 5; ++st) {
    float *ir, *ii, *pr, *pi;
    if (st & 1) { ir = Br; ii = Bi; pr = Ar; pi = Ai; }
    else        { ir = Ar; ii = Ai; pr = Br; pi = Bi; }
    const int quarter = 1 << (2 * st);
    const int p = u & (quarter - 1);
    const int g = u >> (2 * st);

    float sw, cw;
    sincospif((float)(2 * p) * (1.0f / (float)(4 << (2 * st))), &sw, &cw);
    const float w1r = cw,                 w1i = (SIGN < 0) ? -sw : sw;
    const float w2r = w1r*w1r - w1i*w1i,  w2i = 2.0f*w1r*w1i;
    const float w3r = w2r*w1r - w2i*w1i,  w3i = w2r*w1i + w2i*w1r;

    float x0r = ir[lpad(u      )], x0i = ii[lpad(u      )];
    float x1r = ir[lpad(u + 256)], x1i = ii[lpad(u + 256)];
    float x2r = ir[lpad(u + 512)], x2i = ii[lpad(u + 512)];
    float x3r = ir[lpad(u + 768)], x3i = ii[lpad(u + 768)];

    float y1r = x1r*w1r - x1i*w1i, y1i = x1r*w1i + x1i*w1r;
    float y2r = x2r*w2r - x2i*w2i, y2i = x2r*w2i + x2i*w2r;
    float y3r = x3r*w3r - x3i*w3i, y3i = x3r*w3i + x3i*w3r;

    float t0r = x0r + y2r, t0i = x0i + y2i;
    float t1r = x0r - y2r, t1i = x0i - y2i;
    float t2r = y1r + y3r, t2i = y1i + y3i;
    float t3r = y1r - y3r, t3i = y1i - y3i;

    float o0r = t0r + t2r, o0i = t0i + t2i;
    float o2r = t0r - t2r, o2i = t0i - t2i;
    float o1r, o1i, o3r, o3i;
    if (SIGN < 0) {
      o1r = t1r + t3i; o1i = t1i - t3r;
      o3r = t1r - t3i; o3i = t1i + t3r;
    } else {
      o1r = t1r - t3i; o1i = t1i + t3r;
      o3r = t1r + t3i; o3i = t1i - t3r;
    }
    const int base = (g << (2 * st + 2)) + p;
    pr[lpad(base              )] = o0r; pi[lpad(base              )] = o0i;
    pr[lpad(base +     quarter)] = o1r; pi[lpad(base +     quarter)] = o1i;
    pr[lpad(base + 2 * quarter)] = o2r; pi[lpad(base + 2 * quarter)] = o2i;
    pr[lpad(base + 3 * quarter)] = o3r; pi[lpad(base + 3 * quarter)] = o3i;
    __syncthreads();
  }
}

// ---------------- forward FFT ----------------
__global__ __launch_bounds__(256) void k_fwd_passA(const float* __restrict__ x,
                                                   float2* __restrict__ ws0)
{
  __shared__ float Ar[PADN], Ai[PADN], Br[PADN], Bi[PADN];
  const int b = swz(blockIdx.x);   // n2
  const int tid = threadIdx.x;
#pragma unroll
  for (int q = 0; q < 4; ++q) {
    int j = tid + 256 * q;         // n1
    Ar[lpad(j)] = x[(size_t)j * 1024 + b];
    Ai[lpad(j)] = 0.0f;
  }
  __syncthreads();
  fft1024<-1>(Ar, Ai, Br, Bi);
#pragma unroll
  for (int q = 0; q < 4; ++q) {
    int k1 = tid + 256 * q;
    int ph = b * k1;               // < 2^20, exact in fp32
    float s, c;
    sincospif((float)ph * (2.0f / 1048576.0f), &s, &c);
    float vr = Br[lpad(k1)], vi = Bi[lpad(k1)];
    ws0[(size_t)b * 1024 + k1] = make_float2(vr * c + vi * s, vi * c - vr * s);
  }
}

__global__ __launch_bounds__(256) void k_fwd_passB(const float2* __restrict__ ws0,
                                                   float2* __restrict__ fhat,
                                                   float* __restrict__ E)
{
  __shared__ float Ar[PADN], Ai[PADN], Br[PADN], Bi[PADN];
  const int b = swz(blockIdx.x);   // k1
  const int tid = threadIdx.x;
#pragma unroll
  for (int q = 0; q < 4; ++q) {
    int j = tid + 256 * q;         // n2
    float2 v = ws0[(size_t)j * 1024 + b];
    Ar[lpad(j)] = v.x; Ai[lpad(j)] = v.y;
  }
  __syncthreads();
  fft1024<-1>(Ar, Ai, Br, Bi);
#pragma unroll
  for (int q = 0; q < 4; ++q) {
    int k2 = tid + 256 * q;
    float vr = Br[lpad(k2)], vi = Bi[lpad(k2)];
    fhat[(size_t)b * 1024 + k2] = make_float2(vr, vi);
    E[(size_t)b * 1024 + k2] = vr * vr + vi * vi;
  }
}

// ---------------- Lagrange basis on nodes x = {0, 1/3, 2/3, 1} --------------
static __device__ __forceinline__ void lag4(float x, float& l0, float& l1,
                                            float& l2, float& l3)
{
  float m0 = x, m1 = x - (1.0f / 3.0f), m2 = x - (2.0f / 3.0f), m3 = x - 1.0f;
  l0 = -4.5f * m1 * m2 * m3;
  l1 = 13.5f * m0 * m2 * m3;
  l2 = -13.5f * m0 * m1 * m3;
  l3 =  4.5f * m0 * m1 * m2;
}

// ---------------- bin weights: W[b][i] = sum_{t in bin b} E(t) L_i(x_t) -----
__global__ __launch_bounds__(256) void k_moments(const float* __restrict__ E,
                                                 double* __restrict__ W)
{
  __shared__ double red[4 * 4];
  const int B = blockIdx.x;
  const int k2 = B ^ 512;
  const int tid = threadIdx.x;
  double a0 = 0, a1 = 0, a2 = 0, a3 = 0;
#pragma unroll
  for (int q = 0; q < 4; ++q) {
    int k1 = tid + 256 * q;
    float e = E[(size_t)k1 * 1024 + k2];
    float l0, l1, l2, l3;
    lag4((float)k1 * (1.0f / 1024.0f), l0, l1, l2, l3);
    a0 += (double)(e * l0); a1 += (double)(e * l1);
    a2 += (double)(e * l2); a3 += (double)(e * l3);
  }
  const int lane = tid & 63, wv = tid >> 6;       // 4 waves
  double pv[4] = { a0, a1, a2, a3 };
#pragma unroll
  for (int j = 0; j < 4; ++j) {
    double v = pv[j];
    for (int off = 32; off; off >>= 1) v += __shfl_down(v, off, 64);
    if (lane == 0) red[wv * 4 + j] = v;
  }
  __syncthreads();
  if (tid < 4)
    W[B * 4 + tid] = red[tid] + red[4 + tid] + red[8 + tid] + red[12 + tid];
}

// ---------------- the whole 50-iteration loop in ONE workgroup --------------
__global__ __launch_bounds__(1024) void k_solve(
    const double* __restrict__ W4, const float* __restrict__ omega_init,
    float* __restrict__ ckeepN, float* __restrict__ omegaF)
{
  __shared__ float red[16 * 8];
  __shared__ double sbd[8];
  const int t = threadIdx.x;
  const int lane = t & 63, wv = t >> 6;

  float Wr[4], fr[4], cnr[4], csr[4];
#pragma unroll
  for (int e = 0; e < 4; ++e) {
    Wr[e] = (float)W4[t * 4 + e];
    fr[e] = (float)((double)t / 1024.0 + (double)e / 3072.0 - 0.5);
    cnr[e] = 0.0f; csr[e] = 0.0f;
  }
  float om0 = omega_init[0], om1 = omega_init[1], om2 = omega_init[2];
  float pm0 = 0.f, pm1 = 0.f, pm2 = 0.f;
  const float TAU2 = TAU_F * TAU_F;

#pragma unroll 1
  for (int n = 0; n < 50; ++n) {
    const bool snap  = (n == 9) || (n == 19) || (n == 29) || (n == 39);
    const bool check = (n == 10) || (n == 20) || (n == 30) || (n == 40);
    const bool keep  = check || (n == 49);

    if (snap) {
#pragma unroll
      for (int e = 0; e < 4; ++e) csr[e] = cnr[e];
      pm0 = om0; pm1 = om1; pm2 = om2;
    }
    if (keep) {                                   // entry state of this iter
      ((float4*)ckeepN)[t] = make_float4(cnr[0], cnr[1], cnr[2], cnr[3]);
      if (t == 0) { omegaF[0] = om0; omegaF[1] = om1; omegaF[2] = om2; }
    }

    float p0 = 0.f, p1 = 0.f, p2 = 0.f, p3 = 0.f, p4 = 0.f, p5 = 0.f,
          p6 = 0.f, p7 = 0.f;
#pragma unroll
    for (int e = 0; e < 4; ++e) {
      const float f = fr[e];
      float a0 = f - om0, a1 = f - om1, a2 = f - om2;
      float d0 = a0 * a0, d1 = a1 * a1, d2 = a2 * a2;
      float w0 = frcp(1.0f + ALPHA_F * (d0 + d1 + TAU2));
      float w1 = frcp(1.0f + ALPHA_F * (d0 + d1 + d2 + TAU2));
      float w2 = frcp(1.0f + ALPHA_F * (d1 + d2 + TAU2));
      float hf = 1.0f - 0.5f * cnr[e];
      float g = hf * hf;
      float gw0 = g * w0 * w0, gw1 = g * w1 * w1, gw2 = g * w2 * w2;
      const float wj = Wr[e];
      p0 += wj * (f * gw0); p1 += wj * (f * gw1); p2 += wj * (f * gw2);
      p3 += wj * gw0;       p4 += wj * gw1;       p5 += wj * gw2;
      float S = w0 + w1 + w2;
      cnr[e] += TAU_F * (S * hf - 1.0f);
      if (check) {
        float hp = 1.0f - 0.5f * csr[e];
        float b0 = f - pm0, b1 = f - pm1, b2 = f - pm2;
        float e0 = b0 * b0, e1 = b1 * b1, e2 = b2 * b2;
        float v0 = frcp(1.0f + ALPHA_F * (e0 + e1 + TAU2));
        float v1 = frcp(1.0f + ALPHA_F * (e0 + e1 + e2 + TAU2));
        float v2 = frcp(1.0f + ALPHA_F * (e1 + e2 + TAU2));
        float q0 = hf * w0 - hp * v0;
        float q1 = hf * w1 - hp * v1;
        float q2 = hf * w2 - hp * v2;
        p6 += wj * (q0 * q0 + q1 * q1 + q2 * q2);
        p7 += wj * ((hp * hp) * (v0 * v0 + v1 * v1 + v2 * v2));
      }
    }

    // DPP wave reduce (VALU only); full sums land in lane 63
    p0 = wave64_sum(p0); p1 = wave64_sum(p1); p2 = wave64_sum(p2);
    p3 = wave64_sum(p3); p4 = wave64_sum(p4); p5 = wave64_sum(p5);
    if (check) { p6 = wave64_sum(p6); p7 = wave64_sum(p7); }
    if (lane == 63) {
      red[wv * 8 + 0] = p0; red[wv * 8 + 1] = p1; red[wv * 8 + 2] = p2;
      red[wv * 8 + 3] = p3; red[wv * 8 + 4] = p4; red[wv * 8 + 5] = p5;
      red[wv * 8 + 6] = p6; red[wv * 8 + 7] = p7;
    }
    __syncthreads();
    if (t < 8) {
      double s = 0.0;
#pragma unroll
      for (int w2 = 0; w2 < 16; ++w2) s += (double)red[w2 * 8 + t];
      sbd[t] = s;
    }
    __syncthreads();
    float no0 = (float)(sbd[0] / sbd[3]);
    float no1 = (float)(sbd[1] / sbd[4]);
    float no2 = (float)(sbd[2] / sbd[5]);
    bool conv = false;
    if (check) {
      bool ud_ok = sbd[6] < 1e-6 * sbd[7];
      float omd = (fabsf(no0 - no2) + fabsf(no1 - no0) + fabsf(no2 - no1))
                  * (1.0f / 3.0f);
      conv = ud_ok && (omd < 1e-6f);
    }
    om0 = no0; om1 = no1; om2 = no2;
    if (conv) break;                 // uniform: same sbd in every thread
  }
}

// ---------------- inverse passA (one block per (mode, k1)) ----------------
__global__ __launch_bounds__(256) void k_inv_A3(
    const float2* __restrict__ fhat, const float* __restrict__ ckeepN,
    const float* __restrict__ omegaF, float2* __restrict__ ws0)
{
  __shared__ float Ar[PADN], Ai[PADN], Br[PADN], Bi[PADN];
  __shared__ float cn4[4096];
  __shared__ float som[3];
  const int tid = threadIdx.x;
  const int mode = blockIdx.x >> 10;
  const int b = swz(blockIdx.x & 1023);   // k1 of s-layout
  for (int i = tid; i < 4096; i += 256) cn4[i] = ckeepN[i];
  if (tid == 0) { som[0] = omegaF[0]; som[1] = omegaF[1]; som[2] = omegaF[2]; }
  __syncthreads();
  const float om0 = som[0], om1 = som[1], om2 = som[2];
  const float TAU2 = TAU_F * TAU_F;
  float l0, l1, l2, l3;
  lag4((float)b * (1.0f / 1024.0f), l0, l1, l2, l3);

#pragma unroll
  for (int q = 0; q < 4; ++q) {
    int j = tid + 256 * q;       // k2 ; bin = j^512, x = b/1024 (block-fixed)
    float2 f = fhat[(size_t)b * 1024 + j];
    int bin = j ^ 512;
    float4 cv = ((const float4*)cn4)[bin];
    float c = l0 * cv.x + l1 * cv.y + l2 * cv.z + l3 * cv.w;
    float hf = 1.0f - 0.5f * c;
    int tt = (bin << 10) | b;
    float freq = (float)tt * (1.0f / 1048576.0f) - 0.5f;
    float a0 = freq - om0, a1 = freq - om1, a2 = freq - om2;
    float d0 = a0 * a0, d1 = a1 * a1, d2 = a2 * a2;
    float den = (mode == 0) ? (d0 + d1) : (mode == 1) ? (d0 + d1 + d2)
                                                      : (d1 + d2);
    float wk = hf / (1.0f + ALPHA_F * (den + TAU2));
    Ar[lpad(j)] = f.x * wk; Ai[lpad(j)] = f.y * wk;
  }
  __syncthreads();
  fft1024<1>(Ar, Ai, Br, Bi);
#pragma unroll
  for (int q = 0; q < 4; ++q) {
    int m1 = tid + 256 * q;
    int ph = b * m1;
    float s, c;
    sincospif((float)ph * (2.0f / 1048576.0f), &s, &c);
    float vr = Br[lpad(m1)], vi = Bi[lpad(m1)];
    ws0[(size_t)mode * 1048576 + (size_t)b * 1024 + m1]
        = make_float2(vr * c - vi * s, vi * c + vr * s);
  }
}

// ---------------- inverse passB (one block per (mode, m1)) ----------------
__global__ __launch_bounds__(256) void k_inv_B3(const float2* __restrict__ ws0,
                                                float* __restrict__ out)
{
  __shared__ float Ar[PADN], Ai[PADN], Br[PADN], Bi[PADN];
  const int mode = blockIdx.x >> 10;
  const int b = swz(blockIdx.x & 1023);   // m1
  const int tid = threadIdx.x;
#pragma unroll
  for (int q = 0; q < 4; ++q) {
    int j = tid + 256 * q;       // n2
    float2 v = ws0[(size_t)mode * 1048576 + (size_t)j * 1024 + b];
    Ar[lpad(j)] = v.x; Ai[lpad(j)] = v.y;
  }
  __syncthreads();
  fft1024<1>(Ar, Ai, Br, Bi);
#pragma unroll
  for (int q = 0; q < 4; ++q) {
    int m2 = tid + 256 * q;
    out[(size_t)mode * 1048576 + (size_t)m2 * 1024 + b]
        = Br[lpad(m2)] * (1.0f / 1048576.0f);
  }
}

// ---------------- host launch ----------------
extern "C" void kernel_launch(void* const* d_in, const int* in_sizes, int n_in,
                              void* d_out, int out_size, void* d_ws, size_t ws_size,
                              hipStream_t stream)
{
  (void)in_sizes; (void)n_in; (void)out_size; (void)ws_size;
  const float* x       = (const float*)d_in[0];
  const float* om_init = (const float*)d_in[1];
  float* out = (float*)d_out;

  char* w = (char*)d_ws;
  const size_t MB = 1024ull * 1024ull;
  float2* fhat     = (float2*)(w);
  float*  E        = (float*)(w + 8 * MB);
  double* W4       = (double*)(w + 12 * MB);            // 4096 doubles (32 KB)
  float*  ckeepN   = (float*)(w + 12 * MB + 32 * 1024); // 4096 floats
  float*  omegaF   = (float*)(w + 12 * MB + 48 * 1024);
  float2* scratch3 = (float2*)(w + 16 * MB);            // 3 x 8 MB

  k_fwd_passA<<<1024, 256, 0, stream>>>(x, scratch3);
  k_fwd_passB<<<1024, 256, 0, stream>>>(scratch3, fhat, E);
  k_moments<<<1024, 256, 0, stream>>>(E, W4);
  k_solve<<<1, 1024, 0, stream>>>(W4, om_init, ckeepN, omegaF);
  k_inv_A3<<<3072, 256, 0, stream>>>(fhat, ckeepN, omegaF, scratch3);
  k_inv_B3<<<3072, 256, 0, stream>>>(scratch3, out);
}

// Round 9
// 222.658 us; speedup vs baseline: 8.0118x; 1.0520x over previous
//
#include <hip/hip_runtime.h>
#include <math.h>

// VMD: T = 2^20, K = 3, 50 iterations.
// Round-9: (1) k_solve tail all-f32: DPP row-16 cross-wave reduce (no serial
// f64 chain), frcp-based omega divides, TAU^2 folded out (1+a*tau^2 == 1.0f
// exactly in f32 -- same as reference's own f32 arithmetic).
// (2) transpose pairs write strided / read contiguous (stores merge in L2
// fire-and-forget; loads were paying 16x L2->L1 line amplification).
// Workspace (~40 MB of ~256 MB):
//   [0,8MB)   f_hat (float2, s-layout: s = k1*1024+k2, t(s) = ((k2^512)<<10)|k1)
//   [8,12MB)  E = |f_hat|^2 (float, s-layout)
//   [12MB..)  W f64[1024*4]; ckeepN float[4096]; omegaF float[4]
//   [16,40MB) scratch3 (3 x 8MB float2) -- FFT intermediates

#define ALPHA_F 2000.0f
#define TAU_F   1e-7f

static __device__ __forceinline__ int lpad(int i) { return i + (i >> 5); }
static __device__ __forceinline__ int swz(int i)  { return ((i & 7) << 7) | (i >> 3); }
static __device__ __forceinline__ float frcp(float x) { return __builtin_amdgcn_rcpf(x); }

#define PADN 1057

// ---------------- DPP reductions (VALU pipe only) ----------------
template<int CTRL>
static __device__ __forceinline__ float dpp_addf(float v)
{
  int r = __builtin_amdgcn_update_dpp(0, __float_as_int(v), CTRL, 0xf, 0xf, true);
  return v + __int_as_float(r);
}
static __device__ __forceinline__ float wave64_sum(float v)
{
  v = dpp_addf<0x111>(v);   // row_shr:1
  v = dpp_addf<0x112>(v);   // row_shr:2
  v = dpp_addf<0x114>(v);   // row_shr:4
  v = dpp_addf<0x118>(v);   // row_shr:8  -> lane 15 of each row = row sum
  v = dpp_addf<0x142>(v);   // row_bcast:15
  v = dpp_addf<0x143>(v);   // row_bcast:31 -> lane 63 = full sum
  return v;
}
static __device__ __forceinline__ float row16_sum(float v)
{
  v = dpp_addf<0x111>(v);
  v = dpp_addf<0x112>(v);
  v = dpp_addf<0x114>(v);
  v = dpp_addf<0x118>(v);   // lane 15 of each 16-lane row = row sum
  return v;
}

// ---------------- 1024-point radix-4 Stockham FFT in LDS ----------------
template<int SIGN>   // -1 = forward (e^{-i}), +1 = inverse (e^{+i}, unscaled)
static __device__ void fft1024(float* Ar, float* Ai, float* Br, float* Bi)
{
  const int u = threadIdx.x;
#pragma unroll
  for (int st = 0; st < 5; ++st) {
    float *ir, *ii, *pr, *pi;
    if (st & 1) { ir = Br; ii = Bi; pr = Ar; pi = Ai; }
    else        { ir = Ar; ii = Ai; pr = Br; pi = Bi; }
    const int quarter = 1 << (2 * st);
    const int p = u & (quarter - 1);
    const int g = u >> (2 * st);

    float sw, cw;
    sincospif((float)(2 * p) * (1.0f / (float)(4 << (2 * st))), &sw, &cw);
    const float w1r = cw,                 w1i = (SIGN < 0) ? -sw : sw;
    const float w2r = w1r*w1r - w1i*w1i,  w2i = 2.0f*w1r*w1i;
    const float w3r = w2r*w1r - w2i*w1i,  w3i = w2r*w1i + w2i*w1r;

    float x0r = ir[lpad(u      )], x0i = ii[lpad(u      )];
    float x1r = ir[lpad(u + 256)], x1i = ii[lpad(u + 256)];
    float x2r = ir[lpad(u + 512)], x2i = ii[lpad(u + 512)];
    float x3r = ir[lpad(u + 768)], x3i = ii[lpad(u + 768)];

    float y1r = x1r*w1r - x1i*w1i, y1i = x1r*w1i + x1i*w1r;
    float y2r = x2r*w2r - x2i*w2i, y2i = x2r*w2i + x2i*w2r;
    float y3r = x3r*w3r - x3i*w3i, y3i = x3r*w3i + x3i*w3r;

    float t0r = x0r + y2r, t0i = x0i + y2i;
    float t1r = x0r - y2r, t1i = x0i - y2i;
    float t2r = y1r + y3r, t2i = y1i + y3i;
    float t3r = y1r - y3r, t3i = y1i - y3i;

    float o0r = t0r + t2r, o0i = t0i + t2i;
    float o2r = t0r - t2r, o2i = t0i - t2i;
    float o1r, o1i, o3r, o3i;
    if (SIGN < 0) {
      o1r = t1r + t3i; o1i = t1i - t3r;
      o3r = t1r - t3i; o3i = t1i + t3r;
    } else {
      o1r = t1r - t3i; o1i = t1i + t3r;
      o3r = t1r + t3i; o3i = t1i - t3r;
    }
    const int base = (g << (2 * st + 2)) + p;
    pr[lpad(base              )] = o0r; pi[lpad(base              )] = o0i;
    pr[lpad(base +     quarter)] = o1r; pi[lpad(base +     quarter)] = o1i;
    pr[lpad(base + 2 * quarter)] = o2r; pi[lpad(base + 2 * quarter)] = o2i;
    pr[lpad(base + 3 * quarter)] = o3r; pi[lpad(base + 3 * quarter)] = o3i;
    __syncthreads();
  }
}

// ---------------- forward FFT ----------------
// passA: FFT over n1 for fixed n2=b; writes ws0[k1*1024 + n2] (strided store,
// merges in L2) so passB reads contiguously.
__global__ __launch_bounds__(256) void k_fwd_passA(const float* __restrict__ x,
                                                   float2* __restrict__ ws0)
{
  __shared__ float Ar[PADN], Ai[PADN], Br[PADN], Bi[PADN];
  const int b = swz(blockIdx.x);   // n2
  const int tid = threadIdx.x;
#pragma unroll
  for (int q = 0; q < 4; ++q) {
    int j = tid + 256 * q;         // n1
    Ar[lpad(j)] = x[(size_t)j * 1024 + b];
    Ai[lpad(j)] = 0.0f;
  }
  __syncthreads();
  fft1024<-1>(Ar, Ai, Br, Bi);
#pragma unroll
  for (int q = 0; q < 4; ++q) {
    int k1 = tid + 256 * q;
    int ph = b * k1;               // < 2^20, exact in fp32
    float s, c;
    sincospif((float)ph * (2.0f / 1048576.0f), &s, &c);
    float vr = Br[lpad(k1)], vi = Bi[lpad(k1)];
    ws0[(size_t)k1 * 1024 + b] = make_float2(vr * c + vi * s, vi * c - vr * s);
  }
}

// passB: FFT over n2 for fixed k1=b; contiguous reads.
__global__ __launch_bounds__(256) void k_fwd_passB(const float2* __restrict__ ws0,
                                                   float2* __restrict__ fhat,
                                                   float* __restrict__ E)
{
  __shared__ float Ar[PADN], Ai[PADN], Br[PADN], Bi[PADN];
  const int b = swz(blockIdx.x);   // k1
  const int tid = threadIdx.x;
#pragma unroll
  for (int q = 0; q < 4; ++q) {
    int j = tid + 256 * q;         // n2
    float2 v = ws0[(size_t)b * 1024 + j];
    Ar[lpad(j)] = v.x; Ai[lpad(j)] = v.y;
  }
  __syncthreads();
  fft1024<-1>(Ar, Ai, Br, Bi);
#pragma unroll
  for (int q = 0; q < 4; ++q) {
    int k2 = tid + 256 * q;
    float vr = Br[lpad(k2)], vi = Bi[lpad(k2)];
    fhat[(size_t)b * 1024 + k2] = make_float2(vr, vi);
    E[(size_t)b * 1024 + k2] = vr * vr + vi * vi;
  }
}

// ---------------- Lagrange basis on nodes x = {0, 1/3, 2/3, 1} --------------
static __device__ __forceinline__ void lag4(float x, float& l0, float& l1,
                                            float& l2, float& l3)
{
  float m0 = x, m1 = x - (1.0f / 3.0f), m2 = x - (2.0f / 3.0f), m3 = x - 1.0f;
  l0 = -4.5f * m1 * m2 * m3;
  l1 = 13.5f * m0 * m2 * m3;
  l2 = -13.5f * m0 * m1 * m3;
  l3 =  4.5f * m0 * m1 * m2;
}

// ---------------- bin weights: W[b][i] = sum_{t in bin b} E(t) L_i(x_t) -----
__global__ __launch_bounds__(256) void k_moments(const float* __restrict__ E,
                                                 double* __restrict__ W)
{
  __shared__ double red[4 * 4];
  const int B = blockIdx.x;
  const int k2 = B ^ 512;
  const int tid = threadIdx.x;
  double a0 = 0, a1 = 0, a2 = 0, a3 = 0;
#pragma unroll
  for (int q = 0; q < 4; ++q) {
    int k1 = tid + 256 * q;
    float e = E[(size_t)k1 * 1024 + k2];
    float l0, l1, l2, l3;
    lag4((float)k1 * (1.0f / 1024.0f), l0, l1, l2, l3);
    a0 += (double)(e * l0); a1 += (double)(e * l1);
    a2 += (double)(e * l2); a3 += (double)(e * l3);
  }
  const int lane = tid & 63, wv = tid >> 6;       // 4 waves
  double pv[4] = { a0, a1, a2, a3 };
#pragma unroll
  for (int j = 0; j < 4; ++j) {
    double v = pv[j];
    for (int off = 32; off; off >>= 1) v += __shfl_down(v, off, 64);
    if (lane == 0) red[wv * 4 + j] = v;
  }
  __syncthreads();
  if (tid < 4)
    W[B * 4 + tid] = red[tid] + red[4 + tid] + red[8 + tid] + red[12 + tid];
}

// ---------------- the whole 50-iteration loop in ONE workgroup --------------
__global__ __launch_bounds__(1024) void k_solve(
    const double* __restrict__ W4, const float* __restrict__ omega_init,
    float* __restrict__ ckeepN, float* __restrict__ omegaF)
{
  __shared__ float red[8 * 16];    // [slot][wave]
  __shared__ float sbf[8];
  const int t = threadIdx.x;
  const int lane = t & 63, wv = t >> 6;

  float Wr[4], fr[4], cnr[4], csr[4];
#pragma unroll
  for (int e = 0; e < 4; ++e) {
    Wr[e] = (float)W4[t * 4 + e];
    fr[e] = (float)((double)t / 1024.0 + (double)e / 3072.0 - 0.5);
    cnr[e] = 0.0f; csr[e] = 0.0f;
  }
  float om0 = omega_init[0], om1 = omega_init[1], om2 = omega_init[2];
  float pm0 = 0.f, pm1 = 0.f, pm2 = 0.f;

#pragma unroll 1
  for (int n = 0; n < 50; ++n) {
    const bool snap  = (n == 9) || (n == 19) || (n == 29) || (n == 39);
    const bool check = (n == 10) || (n == 20) || (n == 30) || (n == 40);
    const bool keep  = check || (n == 49);

    if (snap) {
#pragma unroll
      for (int e = 0; e < 4; ++e) csr[e] = cnr[e];
      pm0 = om0; pm1 = om1; pm2 = om2;
    }
    if (keep) {                                   // entry state of this iter
      ((float4*)ckeepN)[t] = make_float4(cnr[0], cnr[1], cnr[2], cnr[3]);
      if (t == 0) { omegaF[0] = om0; omegaF[1] = om1; omegaF[2] = om2; }
    }

    float p0 = 0.f, p1 = 0.f, p2 = 0.f, p3 = 0.f, p4 = 0.f, p5 = 0.f,
          p6 = 0.f, p7 = 0.f;
#pragma unroll
    for (int e = 0; e < 4; ++e) {
      const float f = fr[e];
      float a0 = f - om0, a1 = f - om1, a2 = f - om2;
      float d0 = a0 * a0, d1 = a1 * a1, d2 = a2 * a2;
      // 1 + ALPHA*TAU^2 == 1.0f exactly in f32 -- TAU2 folded out
      float w0 = frcp(1.0f + ALPHA_F * (d0 + d1));
      float w1 = frcp(1.0f + ALPHA_F * (d0 + d1 + d2));
      float w2 = frcp(1.0f + ALPHA_F * (d1 + d2));
      float hf = 1.0f - 0.5f * cnr[e];
      float g = hf * hf;
      float gw0 = g * w0 * w0, gw1 = g * w1 * w1, gw2 = g * w2 * w2;
      const float wj = Wr[e];
      p0 += wj * (f * gw0); p1 += wj * (f * gw1); p2 += wj * (f * gw2);
      p3 += wj * gw0;       p4 += wj * gw1;       p5 += wj * gw2;
      float S = w0 + w1 + w2;
      cnr[e] += TAU_F * (S * hf - 1.0f);
      if (check) {
        float hp = 1.0f - 0.5f * csr[e];
        float b0 = f - pm0, b1 = f - pm1, b2 = f - pm2;
        float e0 = b0 * b0, e1 = b1 * b1, e2 = b2 * b2;
        float v0 = frcp(1.0f + ALPHA_F * (e0 + e1));
        float v1 = frcp(1.0f + ALPHA_F * (e0 + e1 + e2));
        float v2 = frcp(1.0f + ALPHA_F * (e1 + e2));
        float q0 = hf * w0 - hp * v0;
        float q1 = hf * w1 - hp * v1;
        float q2 = hf * w2 - hp * v2;
        p6 += Wr[e] * (q0 * q0 + q1 * q1 + q2 * q2);
        p7 += Wr[e] * ((hp * hp) * (v0 * v0 + v1 * v1 + v2 * v2));
      }
    }

    // stage 1: DPP wave reduce; lane 63 stores into [slot][wave]
    p0 = wave64_sum(p0); p1 = wave64_sum(p1); p2 = wave64_sum(p2);
    p3 = wave64_sum(p3); p4 = wave64_sum(p4); p5 = wave64_sum(p5);
    if (check) { p6 = wave64_sum(p6); p7 = wave64_sum(p7); }
    if (lane == 63) {
      red[0 * 16 + wv] = p0; red[1 * 16 + wv] = p1; red[2 * 16 + wv] = p2;
      red[3 * 16 + wv] = p3; red[4 * 16 + wv] = p4; red[5 * 16 + wv] = p5;
      red[6 * 16 + wv] = p6; red[7 * 16 + wv] = p7;
    }
    __syncthreads();
    // stage 2: waves 0-1, each 16-lane row sums one slot's 16 wave-partials
    if (t < 128) {
      float v = red[t];              // [slot = t>>4][idx = t&15]
      v = row16_sum(v);
      if ((t & 15) == 15) sbf[t >> 4] = v;
    }
    __syncthreads();
    float no0 = sbf[0] * frcp(sbf[3]);
    float no1 = sbf[1] * frcp(sbf[4]);
    float no2 = sbf[2] * frcp(sbf[5]);
    bool conv = false;
    if (check) {
      bool ud_ok = sbf[6] < 1e-6f * sbf[7];
      float omd = (fabsf(no0 - no2) + fabsf(no1 - no0) + fabsf(no2 - no1))
                  * (1.0f / 3.0f);
      conv = ud_ok && (omd < 1e-6f);
    }
    om0 = no0; om1 = no1; om2 = no2;
    if (conv) break;                 // uniform: same sbf in every thread
  }
}

// ---------------- inverse passA (one block per (mode, k1)) ----------------
// writes ws0[mode][m1*1024 + k1] (strided store) so inv_B3 reads contiguously.
__global__ __launch_bounds__(256) void k_inv_A3(
    const float2* __restrict__ fhat, const float* __restrict__ ckeepN,
    const float* __restrict__ omegaF, float2* __restrict__ ws0)
{
  __shared__ float Ar[PADN], Ai[PADN], Br[PADN], Bi[PADN];
  __shared__ float cn4[4096];
  __shared__ float som[3];
  const int tid = threadIdx.x;
  const int mode = blockIdx.x >> 10;
  const int b = swz(blockIdx.x & 1023);   // k1 of s-layout
  for (int i = tid; i < 4096; i += 256) cn4[i] = ckeepN[i];
  if (tid == 0) { som[0] = omegaF[0]; som[1] = omegaF[1]; som[2] = omegaF[2]; }
  __syncthreads();
  const float om0 = som[0], om1 = som[1], om2 = som[2];
  const float TAU2 = TAU_F * TAU_F;
  float l0, l1, l2, l3;
  lag4((float)b * (1.0f / 1024.0f), l0, l1, l2, l3);

#pragma unroll
  for (int q = 0; q < 4; ++q) {
    int j = tid + 256 * q;       // k2 ; bin = j^512, x = b/1024 (block-fixed)
    float2 f = fhat[(size_t)b * 1024 + j];
    int bin = j ^ 512;
    float4 cv = ((const float4*)cn4)[bin];
    float c = l0 * cv.x + l1 * cv.y + l2 * cv.z + l3 * cv.w;
    float hf = 1.0f - 0.5f * c;
    int tt = (bin << 10) | b;
    float freq = (float)tt * (1.0f / 1048576.0f) - 0.5f;
    float a0 = freq - om0, a1 = freq - om1, a2 = freq - om2;
    float d0 = a0 * a0, d1 = a1 * a1, d2 = a2 * a2;
    float den = (mode == 0) ? (d0 + d1) : (mode == 1) ? (d0 + d1 + d2)
                                                      : (d1 + d2);
    float wk = hf / (1.0f + ALPHA_F * (den + TAU2));
    Ar[lpad(j)] = f.x * wk; Ai[lpad(j)] = f.y * wk;
  }
  __syncthreads();
  fft1024<1>(Ar, Ai, Br, Bi);
#pragma unroll
  for (int q = 0; q < 4; ++q) {
    int m1 = tid + 256 * q;
    int ph = b * m1;
    float s, c;
    sincospif((float)ph * (2.0f / 1048576.0f), &s, &c);
    float vr = Br[lpad(m1)], vi = Bi[lpad(m1)];
    ws0[(size_t)mode * 1048576 + (size_t)m1 * 1024 + b]
        = make_float2(vr * c - vi * s, vi * c + vr * s);
  }
}

// ---------------- inverse passB (one block per (mode, m1)) ----------------
__global__ __launch_bounds__(256) void k_inv_B3(const float2* __restrict__ ws0,
                                                float* __restrict__ out)
{
  __shared__ float Ar[PADN], Ai[PADN], Br[PADN], Bi[PADN];
  const int mode = blockIdx.x >> 10;
  const int b = swz(blockIdx.x & 1023);   // m1
  const int tid = threadIdx.x;
#pragma unroll
  for (int q = 0; q < 4; ++q) {
    int j = tid + 256 * q;       // contiguous read of row m1=b
    float2 v = ws0[(size_t)mode * 1048576 + (size_t)b * 1024 + j];
    Ar[lpad(j)] = v.x; Ai[lpad(j)] = v.y;
  }
  __syncthreads();
  fft1024<1>(Ar, Ai, Br, Bi);
#pragma unroll
  for (int q = 0; q < 4; ++q) {
    int m2 = tid + 256 * q;
    out[(size_t)mode * 1048576 + (size_t)m2 * 1024 + b]
        = Br[lpad(m2)] * (1.0f / 1048576.0f);
  }
}

// ---------------- host launch ----------------
extern "C" void kernel_launch(void* const* d_in, const int* in_sizes, int n_in,
                              void* d_out, int out_size, void* d_ws, size_t ws_size,
                              hipStream_t stream)
{
  (void)in_sizes; (void)n_in; (void)out_size; (void)ws_size;
  const float* x       = (const float*)d_in[0];
  const float* om_init = (const float*)d_in[1];
  float* out = (float*)d_out;

  char* w = (char*)d_ws;
  const size_t MB = 1024ull * 1024ull;
  float2* fhat     = (float2*)(w);
  float*  E        = (float*)(w + 8 * MB);
  double* W4       = (double*)(w + 12 * MB);            // 4096 doubles (32 KB)
  float*  ckeepN   = (float*)(w + 12 * MB + 32 * 1024); // 4096 floats
  float*  omegaF   = (float*)(w + 12 * MB + 48 * 1024);
  float2* scratch3 = (float2*)(w + 16 * MB);            // 3 x 8 MB

  k_fwd_passA<<<1024, 256, 0, stream>>>(x, scratch3);
  k_fwd_passB<<<1024, 256, 0, stream>>>(scratch3, fhat, E);
  k_moments<<<1024, 256, 0, stream>>>(E, W4);
  k_solve<<<1, 1024, 0, stream>>>(W4, om_init, ckeepN, omegaF);
  k_inv_A3<<<3072, 256, 0, stream>>>(fhat, ckeepN, omegaF, scratch3);
  k_inv_B3<<<3072, 256, 0, stream>>>(scratch3, out);
}

// Round 10
// 217.326 us; speedup vs baseline: 8.2083x; 1.0245x over previous
//
#include <hip/hip_runtime.h>
#include <math.h>

// VMD: T = 2^20, K = 3, 50 iterations.
// Round-10: (1) Hermitian packing: Re(ifft(U_k)) = ifft(V_k), V_k = fhat*ravg_k
// (ravg_k(f) = (r_k(f)+r_k(-f))/2, local -- fhat Hermitian since x real).
// V0,V1 packed into ONE complex inverse FFT (Re->imf0, Im->imf1); V2 alone.
// 3 inverse FFTs -> 2.  (2) float2-LDS FFT (ds b64, half the LDS ops),
// stage-0 identity twiddle skipped.
// Workspace (~40 MB of ~256 MB):
//   [0,8MB)   f_hat (float2, s-layout: s = k1*1024+k2, t(s) = ((k2^512)<<10)|k1)
//   [8,12MB)  E = |f_hat|^2 (float, s-layout)
//   [12MB..)  W f64[1024*4]; ckeepN float[4096]; omegaF float[4]
//   [16,32MB) scratch (2 x 8MB float2) -- FFT intermediates

#define ALPHA_F 2000.0f
#define TAU_F   1e-7f

static __device__ __forceinline__ int lpad2(int i) { return i + (i >> 4); }
static __device__ __forceinline__ int swz(int i)  { return ((i & 7) << 7) | (i >> 3); }
static __device__ __forceinline__ float frcp(float x) { return __builtin_amdgcn_rcpf(x); }

#define PADN2 1088

// ---------------- DPP reductions (VALU pipe only) ----------------
template<int CTRL>
static __device__ __forceinline__ float dpp_addf(float v)
{
  int r = __builtin_amdgcn_update_dpp(0, __float_as_int(v), CTRL, 0xf, 0xf, true);
  return v + __int_as_float(r);
}
static __device__ __forceinline__ float wave64_sum(float v)
{
  v = dpp_addf<0x111>(v);   // row_shr:1
  v = dpp_addf<0x112>(v);   // row_shr:2
  v = dpp_addf<0x114>(v);   // row_shr:4
  v = dpp_addf<0x118>(v);   // row_shr:8
  v = dpp_addf<0x142>(v);   // row_bcast:15
  v = dpp_addf<0x143>(v);   // row_bcast:31 -> lane 63 = full sum
  return v;
}
static __device__ __forceinline__ float row16_sum(float v)
{
  v = dpp_addf<0x111>(v);
  v = dpp_addf<0x112>(v);
  v = dpp_addf<0x114>(v);
  v = dpp_addf<0x118>(v);   // lane 15 of each 16-lane row = row sum
  return v;
}

// ---------------- 1024-point radix-4 Stockham FFT, float2 LDS ----------------
template<int SIGN>   // -1 = forward (e^{-i}), +1 = inverse (e^{+i}, unscaled)
static __device__ void fft1024c(float2* A, float2* B)   // in A, out B
{
  const int u = threadIdx.x;
#pragma unroll
  for (int st = 0; st < 5; ++st) {
    float2 *in  = (st & 1) ? B : A;
    float2 *out = (st & 1) ? A : B;
    const int quarter = 1 << (2 * st);
    const int p = u & (quarter - 1);
    const int g = u >> (2 * st);

    float w1r, w1i;
    if (st == 0) { w1r = 1.0f; w1i = 0.0f; }
    else {
      float sw, cw;
      sincospif((float)(2 * p) * (1.0f / (float)(4 << (2 * st))), &sw, &cw);
      w1r = cw; w1i = (SIGN < 0) ? -sw : sw;
    }
    const float w2r = w1r*w1r - w1i*w1i,  w2i = 2.0f*w1r*w1i;
    const float w3r = w2r*w1r - w2i*w1i,  w3i = w2r*w1i + w2i*w1r;

    float2 X0 = in[lpad2(u      )];
    float2 X1 = in[lpad2(u + 256)];
    float2 X2 = in[lpad2(u + 512)];
    float2 X3 = in[lpad2(u + 768)];

    float y1r = X1.x*w1r - X1.y*w1i, y1i = X1.x*w1i + X1.y*w1r;
    float y2r = X2.x*w2r - X2.y*w2i, y2i = X2.x*w2i + X2.y*w2r;
    float y3r = X3.x*w3r - X3.y*w3i, y3i = X3.x*w3i + X3.y*w3r;

    float t0r = X0.x + y2r, t0i = X0.y + y2i;
    float t1r = X0.x - y2r, t1i = X0.y - y2i;
    float t2r = y1r + y3r,  t2i = y1i + y3i;
    float t3r = y1r - y3r,  t3i = y1i - y3i;

    float o0r = t0r + t2r, o0i = t0i + t2i;
    float o2r = t0r - t2r, o2i = t0i - t2i;
    float o1r, o1i, o3r, o3i;
    if (SIGN < 0) {
      o1r = t1r + t3i; o1i = t1i - t3r;
      o3r = t1r - t3i; o3i = t1i + t3r;
    } else {
      o1r = t1r - t3i; o1i = t1i + t3r;
      o3r = t1r + t3i; o3i = t1i - t3r;
    }
    const int base = (g << (2 * st + 2)) + p;
    out[lpad2(base              )] = make_float2(o0r, o0i);
    out[lpad2(base +     quarter)] = make_float2(o1r, o1i);
    out[lpad2(base + 2 * quarter)] = make_float2(o2r, o2i);
    out[lpad2(base + 3 * quarter)] = make_float2(o3r, o3i);
    __syncthreads();
  }
}

// ---------------- forward FFT ----------------
__global__ __launch_bounds__(256) void k_fwd_passA(const float* __restrict__ x,
                                                   float2* __restrict__ ws0)
{
  __shared__ float2 A[PADN2], B[PADN2];
  const int b = swz(blockIdx.x);   // n2
  const int tid = threadIdx.x;
#pragma unroll
  for (int q = 0; q < 4; ++q) {
    int j = tid + 256 * q;         // n1
    A[lpad2(j)] = make_float2(x[(size_t)j * 1024 + b], 0.0f);
  }
  __syncthreads();
  fft1024c<-1>(A, B);
#pragma unroll
  for (int q = 0; q < 4; ++q) {
    int k1 = tid + 256 * q;
    int ph = b * k1;               // < 2^20, exact in fp32
    float s, c;
    sincospif((float)ph * (2.0f / 1048576.0f), &s, &c);
    float2 v = B[lpad2(k1)];
    ws0[(size_t)k1 * 1024 + b] = make_float2(v.x * c + v.y * s, v.y * c - v.x * s);
  }
}

__global__ __launch_bounds__(256) void k_fwd_passB(const float2* __restrict__ ws0,
                                                   float2* __restrict__ fhat,
                                                   float* __restrict__ E)
{
  __shared__ float2 A[PADN2], B[PADN2];
  const int b = swz(blockIdx.x);   // k1
  const int tid = threadIdx.x;
#pragma unroll
  for (int q = 0; q < 4; ++q) {
    int j = tid + 256 * q;         // n2 ; contiguous read
    A[lpad2(j)] = ws0[(size_t)b * 1024 + j];
  }
  __syncthreads();
  fft1024c<-1>(A, B);
#pragma unroll
  for (int q = 0; q < 4; ++q) {
    int k2 = tid + 256 * q;
    float2 v = B[lpad2(k2)];
    fhat[(size_t)b * 1024 + k2] = v;
    E[(size_t)b * 1024 + k2] = v.x * v.x + v.y * v.y;
  }
}

// ---------------- Lagrange basis on nodes x = {0, 1/3, 2/3, 1} --------------
static __device__ __forceinline__ void lag4(float x, float& l0, float& l1,
                                            float& l2, float& l3)
{
  float m0 = x, m1 = x - (1.0f / 3.0f), m2 = x - (2.0f / 3.0f), m3 = x - 1.0f;
  l0 = -4.5f * m1 * m2 * m3;
  l1 = 13.5f * m0 * m2 * m3;
  l2 = -13.5f * m0 * m1 * m3;
  l3 =  4.5f * m0 * m1 * m2;
}

// ---------------- bin weights: W[b][i] = sum_{t in bin b} E(t) L_i(x_t) -----
__global__ __launch_bounds__(256) void k_moments(const float* __restrict__ E,
                                                 double* __restrict__ W)
{
  __shared__ double red[4 * 4];
  const int B = blockIdx.x;
  const int k2 = B ^ 512;
  const int tid = threadIdx.x;
  double a0 = 0, a1 = 0, a2 = 0, a3 = 0;
#pragma unroll
  for (int q = 0; q < 4; ++q) {
    int k1 = tid + 256 * q;
    float e = E[(size_t)k1 * 1024 + k2];
    float l0, l1, l2, l3;
    lag4((float)k1 * (1.0f / 1024.0f), l0, l1, l2, l3);
    a0 += (double)(e * l0); a1 += (double)(e * l1);
    a2 += (double)(e * l2); a3 += (double)(e * l3);
  }
  const int lane = tid & 63, wv = tid >> 6;       // 4 waves
  double pv[4] = { a0, a1, a2, a3 };
#pragma unroll
  for (int j = 0; j < 4; ++j) {
    double v = pv[j];
    for (int off = 32; off; off >>= 1) v += __shfl_down(v, off, 64);
    if (lane == 0) red[wv * 4 + j] = v;
  }
  __syncthreads();
  if (tid < 4)
    W[B * 4 + tid] = red[tid] + red[4 + tid] + red[8 + tid] + red[12 + tid];
}

// ---------------- the whole 50-iteration loop in ONE workgroup --------------
__global__ __launch_bounds__(1024) void k_solve(
    const double* __restrict__ W4, const float* __restrict__ omega_init,
    float* __restrict__ ckeepN, float* __restrict__ omegaF)
{
  __shared__ float red[8 * 16];    // [slot][wave]
  __shared__ float sbf[8];
  const int t = threadIdx.x;
  const int lane = t & 63, wv = t >> 6;

  float Wr[4], fr[4], cnr[4], csr[4];
#pragma unroll
  for (int e = 0; e < 4; ++e) {
    Wr[e] = (float)W4[t * 4 + e];
    fr[e] = (float)((double)t / 1024.0 + (double)e / 3072.0 - 0.5);
    cnr[e] = 0.0f; csr[e] = 0.0f;
  }
  float om0 = omega_init[0], om1 = omega_init[1], om2 = omega_init[2];
  float pm0 = 0.f, pm1 = 0.f, pm2 = 0.f;

#pragma unroll 1
  for (int n = 0; n < 50; ++n) {
    const bool snap  = (n == 9) || (n == 19) || (n == 29) || (n == 39);
    const bool check = (n == 10) || (n == 20) || (n == 30) || (n == 40);
    const bool keep  = check || (n == 49);

    if (snap) {
#pragma unroll
      for (int e = 0; e < 4; ++e) csr[e] = cnr[e];
      pm0 = om0; pm1 = om1; pm2 = om2;
    }
    if (keep) {
      ((float4*)ckeepN)[t] = make_float4(cnr[0], cnr[1], cnr[2], cnr[3]);
      if (t == 0) { omegaF[0] = om0; omegaF[1] = om1; omegaF[2] = om2; }
    }

    float p0 = 0.f, p1 = 0.f, p2 = 0.f, p3 = 0.f, p4 = 0.f, p5 = 0.f,
          p6 = 0.f, p7 = 0.f;
#pragma unroll
    for (int e = 0; e < 4; ++e) {
      const float f = fr[e];
      float a0 = f - om0, a1 = f - om1, a2 = f - om2;
      float d0 = a0 * a0, d1 = a1 * a1, d2 = a2 * a2;
      float w0 = frcp(1.0f + ALPHA_F * (d0 + d1));
      float w1 = frcp(1.0f + ALPHA_F * (d0 + d1 + d2));
      float w2 = frcp(1.0f + ALPHA_F * (d1 + d2));
      float hf = 1.0f - 0.5f * cnr[e];
      float g = hf * hf;
      float gw0 = g * w0 * w0, gw1 = g * w1 * w1, gw2 = g * w2 * w2;
      const float wj = Wr[e];
      p0 += wj * (f * gw0); p1 += wj * (f * gw1); p2 += wj * (f * gw2);
      p3 += wj * gw0;       p4 += wj * gw1;       p5 += wj * gw2;
      float S = w0 + w1 + w2;
      cnr[e] += TAU_F * (S * hf - 1.0f);
      if (check) {
        float hp = 1.0f - 0.5f * csr[e];
        float b0 = f - pm0, b1 = f - pm1, b2 = f - pm2;
        float e0 = b0 * b0, e1 = b1 * b1, e2 = b2 * b2;
        float v0 = frcp(1.0f + ALPHA_F * (e0 + e1));
        float v1 = frcp(1.0f + ALPHA_F * (e0 + e1 + e2));
        float v2 = frcp(1.0f + ALPHA_F * (e1 + e2));
        float q0 = hf * w0 - hp * v0;
        float q1 = hf * w1 - hp * v1;
        float q2 = hf * w2 - hp * v2;
        p6 += Wr[e] * (q0 * q0 + q1 * q1 + q2 * q2);
        p7 += Wr[e] * ((hp * hp) * (v0 * v0 + v1 * v1 + v2 * v2));
      }
    }

    p0 = wave64_sum(p0); p1 = wave64_sum(p1); p2 = wave64_sum(p2);
    p3 = wave64_sum(p3); p4 = wave64_sum(p4); p5 = wave64_sum(p5);
    if (check) { p6 = wave64_sum(p6); p7 = wave64_sum(p7); }
    if (lane == 63) {
      red[0 * 16 + wv] = p0; red[1 * 16 + wv] = p1; red[2 * 16 + wv] = p2;
      red[3 * 16 + wv] = p3; red[4 * 16 + wv] = p4; red[5 * 16 + wv] = p5;
      red[6 * 16 + wv] = p6; red[7 * 16 + wv] = p7;
    }
    __syncthreads();
    if (t < 128) {
      float v = red[t];
      v = row16_sum(v);
      if ((t & 15) == 15) sbf[t >> 4] = v;
    }
    __syncthreads();
    float no0 = sbf[0] * frcp(sbf[3]);
    float no1 = sbf[1] * frcp(sbf[4]);
    float no2 = sbf[2] * frcp(sbf[5]);
    bool conv = false;
    if (check) {
      bool ud_ok = sbf[6] < 1e-6f * sbf[7];
      float omd = (fabsf(no0 - no2) + fabsf(no1 - no0) + fabsf(no2 - no1))
                  * (1.0f / 3.0f);
      conv = ud_ok && (omd < 1e-6f);
    }
    om0 = no0; om1 = no1; om2 = no2;
    if (conv) break;
  }
}

// ---------------- inverse passA: pk=0 -> V0 + i*V1 packed ; pk=1 -> V2 ------
// V_k(f) = fhat(f) * ravg_k(f),  ravg_k = (r_k(f) + r_k(-f))/2, r_k = hf*w_k.
// Partner c interpolated at (bin' = 1023-bin, x' = 1 - b/1024) from the same
// node table (partner-of-partner symmetry => V exactly Hermitian per pair).
__global__ __launch_bounds__(256) void k_inv_A2(
    const float2* __restrict__ fhat, const float* __restrict__ ckeepN,
    const float* __restrict__ omegaF, float2* __restrict__ ws0)
{
  __shared__ float2 A[PADN2], B[PADN2];
  __shared__ float cn4[4096];
  __shared__ float som[3];
  const int tid = threadIdx.x;
  const int pk = blockIdx.x >> 10;
  const int b = swz(blockIdx.x & 1023);   // k1 of s-layout
  for (int i = tid; i < 4096; i += 256) cn4[i] = ckeepN[i];
  if (tid == 0) { som[0] = omegaF[0]; som[1] = omegaF[1]; som[2] = omegaF[2]; }
  __syncthreads();
  const float om0 = som[0], om1 = som[1], om2 = som[2];
  const float xb = (float)b * (1.0f / 1024.0f);
  float l0, l1, l2, l3, m0, m1, m2, m3;
  lag4(xb, l0, l1, l2, l3);
  lag4(1.0f - xb, m0, m1, m2, m3);

#pragma unroll
  for (int q = 0; q < 4; ++q) {
    int j = tid + 256 * q;       // k2
    float2 f = fhat[(size_t)b * 1024 + j];
    int bin = j ^ 512;
    int binp = 1023 - bin;
    float4 cv = ((const float4*)cn4)[bin];
    float4 cw = ((const float4*)cn4)[binp];
    float c  = l0 * cv.x + l1 * cv.y + l2 * cv.z + l3 * cv.w;
    float cp = m0 * cw.x + m1 * cw.y + m2 * cw.z + m3 * cw.w;
    float hf = 1.0f - 0.5f * c;
    float hp = 1.0f - 0.5f * cp;
    int tt = (bin << 10) | b;
    float freq = (float)tt * (1.0f / 1048576.0f) - 0.5f;
    float a0 = freq - om0, a1 = freq - om1, a2 = freq - om2;
    float d0 = a0 * a0, d1 = a1 * a1, d2 = a2 * a2;
    float g0 = -freq - om0, g1 = -freq - om1, g2 = -freq - om2;
    float e0 = g0 * g0, e1 = g1 * g1, e2 = g2 * g2;
    float2 V;
    if (pk == 0) {
      float r0  = hf * frcp(1.0f + ALPHA_F * (d0 + d1));
      float r0n = hp * frcp(1.0f + ALPHA_F * (e0 + e1));
      float r1  = hf * frcp(1.0f + ALPHA_F * (d0 + d1 + d2));
      float r1n = hp * frcp(1.0f + ALPHA_F * (e0 + e1 + e2));
      float Rr = 0.5f * (r0 + r0n);
      float Ri = 0.5f * (r1 + r1n);
      V = make_float2(f.x * Rr - f.y * Ri, f.x * Ri + f.y * Rr);
    } else {
      float r2  = hf * frcp(1.0f + ALPHA_F * (d1 + d2));
      float r2n = hp * frcp(1.0f + ALPHA_F * (e1 + e2));
      float Rr = 0.5f * (r2 + r2n);
      V = make_float2(f.x * Rr, f.y * Rr);
    }
    A[lpad2(j)] = V;
  }
  __syncthreads();
  fft1024c<1>(A, B);
#pragma unroll
  for (int q = 0; q < 4; ++q) {
    int m1i = tid + 256 * q;
    int ph = b * m1i;
    float s, c;
    sincospif((float)ph * (2.0f / 1048576.0f), &s, &c);
    float2 v = B[lpad2(m1i)];
    ws0[(size_t)pk * 1048576 + (size_t)m1i * 1024 + b]
        = make_float2(v.x * c - v.y * s, v.y * c + v.x * s);
  }
}

// ---------------- inverse passB: pk=0 -> out0=Re,out1=Im ; pk=1 -> out2=Re --
__global__ __launch_bounds__(256) void k_inv_B2(const float2* __restrict__ ws0,
                                                float* __restrict__ out)
{
  __shared__ float2 A[PADN2], B[PADN2];
  const int pk = blockIdx.x >> 10;
  const int b = swz(blockIdx.x & 1023);   // m1
  const int tid = threadIdx.x;
#pragma unroll
  for (int q = 0; q < 4; ++q) {
    int j = tid + 256 * q;       // contiguous read of row m1=b
    A[lpad2(j)] = ws0[(size_t)pk * 1048576 + (size_t)b * 1024 + j];
  }
  __syncthreads();
  fft1024c<1>(A, B);
  const float sc = 1.0f / 1048576.0f;
#pragma unroll
  for (int q = 0; q < 4; ++q) {
    int m2 = tid + 256 * q;
    float2 v = B[lpad2(m2)];
    if (pk == 0) {
      out[(size_t)m2 * 1024 + b]           = v.x * sc;   // imf0
      out[1048576 + (size_t)m2 * 1024 + b] = v.y * sc;   // imf1
    } else {
      out[2097152 + (size_t)m2 * 1024 + b] = v.x * sc;   // imf2
    }
  }
}

// ---------------- host launch ----------------
extern "C" void kernel_launch(void* const* d_in, const int* in_sizes, int n_in,
                              void* d_out, int out_size, void* d_ws, size_t ws_size,
                              hipStream_t stream)
{
  (void)in_sizes; (void)n_in; (void)out_size; (void)ws_size;
  const float* x       = (const float*)d_in[0];
  const float* om_init = (const float*)d_in[1];
  float* out = (float*)d_out;

  char* w = (char*)d_ws;
  const size_t MB = 1024ull * 1024ull;
  float2* fhat     = (float2*)(w);
  float*  E        = (float*)(w + 8 * MB);
  double* W4       = (double*)(w + 12 * MB);            // 4096 doubles (32 KB)
  float*  ckeepN   = (float*)(w + 12 * MB + 32 * 1024); // 4096 floats
  float*  omegaF   = (float*)(w + 12 * MB + 48 * 1024);
  float2* scratch  = (float2*)(w + 16 * MB);            // 2 x 8 MB

  k_fwd_passA<<<1024, 256, 0, stream>>>(x, scratch);
  k_fwd_passB<<<1024, 256, 0, stream>>>(scratch, fhat, E);
  k_moments<<<1024, 256, 0, stream>>>(E, W4);
  k_solve<<<1, 1024, 0, stream>>>(W4, om_init, ckeepN, omegaF);
  k_inv_A2<<<2048, 256, 0, stream>>>(fhat, ckeepN, omegaF, scratch);
  k_inv_B2<<<2048, 256, 0, stream>>>(scratch, out);
}

// Round 11
// 212.148 us; speedup vs baseline: 8.4087x; 1.0244x over previous
//
#include <hip/hip_runtime.h>
#include <math.h>

// VMD: T = 2^20, K = 3, 50 iterations.
// Round-11: k_solve loop peeled at COMPILE TIME into plain/check/snap bodies.
// Theory: the runtime `if (check)` inside the n-loop was if-converted by the
// compiler, executing the convergence-diff math (6 rcp + ~25 VALU per node)
// in all 50 iterations; k_solve's measured issue rate (~3150 cyc/iter) is ~2x
// the plain-body instruction count (~1400). Structural peel makes plain iters
// contain no check code. Math order unchanged -> bit-identical omega path.
// Everything else identical to round 10 (217 us, absmax 1.95e-3).
// Workspace (~40 MB of ~256 MB):
//   [0,8MB)   f_hat (float2, s-layout: s = k1*1024+k2, t(s) = ((k2^512)<<10)|k1)
//   [8,12MB)  E = |f_hat|^2 (float, s-layout)
//   [12MB..)  W f64[1024*4]; ckeepN float[4096]; omegaF float[4]
//   [16,32MB) scratch (2 x 8MB float2) -- FFT intermediates

#define ALPHA_F 2000.0f
#define TAU_F   1e-7f

static __device__ __forceinline__ int lpad2(int i) { return i + (i >> 4); }
static __device__ __forceinline__ int swz(int i)  { return ((i & 7) << 7) | (i >> 3); }
static __device__ __forceinline__ float frcp(float x) { return __builtin_amdgcn_rcpf(x); }

#define PADN2 1088

// ---------------- DPP reductions (VALU pipe only) ----------------
template<int CTRL>
static __device__ __forceinline__ float dpp_addf(float v)
{
  int r = __builtin_amdgcn_update_dpp(0, __float_as_int(v), CTRL, 0xf, 0xf, true);
  return v + __int_as_float(r);
}
static __device__ __forceinline__ float wave64_sum(float v)
{
  v = dpp_addf<0x111>(v);   // row_shr:1
  v = dpp_addf<0x112>(v);   // row_shr:2
  v = dpp_addf<0x114>(v);   // row_shr:4
  v = dpp_addf<0x118>(v);   // row_shr:8
  v = dpp_addf<0x142>(v);   // row_bcast:15
  v = dpp_addf<0x143>(v);   // row_bcast:31 -> lane 63 = full sum
  return v;
}
static __device__ __forceinline__ float row16_sum(float v)
{
  v = dpp_addf<0x111>(v);
  v = dpp_addf<0x112>(v);
  v = dpp_addf<0x114>(v);
  v = dpp_addf<0x118>(v);   // lane 15 of each 16-lane row = row sum
  return v;
}

// ---------------- 1024-point radix-4 Stockham FFT, float2 LDS ----------------
template<int SIGN>   // -1 = forward (e^{-i}), +1 = inverse (e^{+i}, unscaled)
static __device__ void fft1024c(float2* A, float2* B)   // in A, out B
{
  const int u = threadIdx.x;
#pragma unroll
  for (int st = 0; st < 5; ++st) {
    float2 *in  = (st & 1) ? B : A;
    float2 *out = (st & 1) ? A : B;
    const int quarter = 1 << (2 * st);
    const int p = u & (quarter - 1);
    const int g = u >> (2 * st);

    float w1r, w1i;
    if (st == 0) { w1r = 1.0f; w1i = 0.0f; }
    else {
      float sw, cw;
      sincospif((float)(2 * p) * (1.0f / (float)(4 << (2 * st))), &sw, &cw);
      w1r = cw; w1i = (SIGN < 0) ? -sw : sw;
    }
    const float w2r = w1r*w1r - w1i*w1i,  w2i = 2.0f*w1r*w1i;
    const float w3r = w2r*w1r - w2i*w1i,  w3i = w2r*w1i + w2i*w1r;

    float2 X0 = in[lpad2(u      )];
    float2 X1 = in[lpad2(u + 256)];
    float2 X2 = in[lpad2(u + 512)];
    float2 X3 = in[lpad2(u + 768)];

    float y1r = X1.x*w1r - X1.y*w1i, y1i = X1.x*w1i + X1.y*w1r;
    float y2r = X2.x*w2r - X2.y*w2i, y2i = X2.x*w2i + X2.y*w2r;
    float y3r = X3.x*w3r - X3.y*w3i, y3i = X3.x*w3i + X3.y*w3r;

    float t0r = X0.x + y2r, t0i = X0.y + y2i;
    float t1r = X0.x - y2r, t1i = X0.y - y2i;
    float t2r = y1r + y3r,  t2i = y1i + y3i;
    float t3r = y1r - y3r,  t3i = y1i - y3i;

    float o0r = t0r + t2r, o0i = t0i + t2i;
    float o2r = t0r - t2r, o2i = t0i - t2i;
    float o1r, o1i, o3r, o3i;
    if (SIGN < 0) {
      o1r = t1r + t3i; o1i = t1i - t3r;
      o3r = t1r - t3i; o3i = t1i + t3r;
    } else {
      o1r = t1r - t3i; o1i = t1i + t3r;
      o3r = t1r + t3i; o3i = t1i - t3r;
    }
    const int base = (g << (2 * st + 2)) + p;
    out[lpad2(base              )] = make_float2(o0r, o0i);
    out[lpad2(base +     quarter)] = make_float2(o1r, o1i);
    out[lpad2(base + 2 * quarter)] = make_float2(o2r, o2i);
    out[lpad2(base + 3 * quarter)] = make_float2(o3r, o3i);
    __syncthreads();
  }
}

// ---------------- forward FFT ----------------
__global__ __launch_bounds__(256) void k_fwd_passA(const float* __restrict__ x,
                                                   float2* __restrict__ ws0)
{
  __shared__ float2 A[PADN2], B[PADN2];
  const int b = swz(blockIdx.x);   // n2
  const int tid = threadIdx.x;
#pragma unroll
  for (int q = 0; q < 4; ++q) {
    int j = tid + 256 * q;         // n1
    A[lpad2(j)] = make_float2(x[(size_t)j * 1024 + b], 0.0f);
  }
  __syncthreads();
  fft1024c<-1>(A, B);
#pragma unroll
  for (int q = 0; q < 4; ++q) {
    int k1 = tid + 256 * q;
    int ph = b * k1;               // < 2^20, exact in fp32
    float s, c;
    sincospif((float)ph * (2.0f / 1048576.0f), &s, &c);
    float2 v = B[lpad2(k1)];
    ws0[(size_t)k1 * 1024 + b] = make_float2(v.x * c + v.y * s, v.y * c - v.x * s);
  }
}

__global__ __launch_bounds__(256) void k_fwd_passB(const float2* __restrict__ ws0,
                                                   float2* __restrict__ fhat,
                                                   float* __restrict__ E)
{
  __shared__ float2 A[PADN2], B[PADN2];
  const int b = swz(blockIdx.x);   // k1
  const int tid = threadIdx.x;
#pragma unroll
  for (int q = 0; q < 4; ++q) {
    int j = tid + 256 * q;         // n2 ; contiguous read
    A[lpad2(j)] = ws0[(size_t)b * 1024 + j];
  }
  __syncthreads();
  fft1024c<-1>(A, B);
#pragma unroll
  for (int q = 0; q < 4; ++q) {
    int k2 = tid + 256 * q;
    float2 v = B[lpad2(k2)];
    fhat[(size_t)b * 1024 + k2] = v;
    E[(size_t)b * 1024 + k2] = v.x * v.x + v.y * v.y;
  }
}

// ---------------- Lagrange basis on nodes x = {0, 1/3, 2/3, 1} --------------
static __device__ __forceinline__ void lag4(float x, float& l0, float& l1,
                                            float& l2, float& l3)
{
  float m0 = x, m1 = x - (1.0f / 3.0f), m2 = x - (2.0f / 3.0f), m3 = x - 1.0f;
  l0 = -4.5f * m1 * m2 * m3;
  l1 = 13.5f * m0 * m2 * m3;
  l2 = -13.5f * m0 * m1 * m3;
  l3 =  4.5f * m0 * m1 * m2;
}

// ---------------- bin weights: W[b][i] = sum_{t in bin b} E(t) L_i(x_t) -----
__global__ __launch_bounds__(256) void k_moments(const float* __restrict__ E,
                                                 double* __restrict__ W)
{
  __shared__ double red[4 * 4];
  const int B = blockIdx.x;
  const int k2 = B ^ 512;
  const int tid = threadIdx.x;
  double a0 = 0, a1 = 0, a2 = 0, a3 = 0;
#pragma unroll
  for (int q = 0; q < 4; ++q) {
    int k1 = tid + 256 * q;
    float e = E[(size_t)k1 * 1024 + k2];
    float l0, l1, l2, l3;
    lag4((float)k1 * (1.0f / 1024.0f), l0, l1, l2, l3);
    a0 += (double)(e * l0); a1 += (double)(e * l1);
    a2 += (double)(e * l2); a3 += (double)(e * l3);
  }
  const int lane = tid & 63, wv = tid >> 6;       // 4 waves
  double pv[4] = { a0, a1, a2, a3 };
#pragma unroll
  for (int j = 0; j < 4; ++j) {
    double v = pv[j];
    for (int off = 32; off; off >>= 1) v += __shfl_down(v, off, 64);
    if (lane == 0) red[wv * 4 + j] = v;
  }
  __syncthreads();
  if (tid < 4)
    W[B * 4 + tid] = red[tid] + red[4 + tid] + red[8 + tid] + red[12 + tid];
}

// ---------------- the whole 50-iteration loop in ONE workgroup --------------
// Compile-time peel: 5 groups of [check(+keep)] + 8 plain + [snap(+keep@49)].
__global__ __launch_bounds__(1024) void k_solve(
    const double* __restrict__ W4, const float* __restrict__ omega_init,
    float* __restrict__ ckeepN, float* __restrict__ omegaF)
{
  __shared__ float red[8 * 16];    // [slot][wave]
  __shared__ float sbf[8];
  const int t = threadIdx.x;
  const int lane = t & 63, wv = t >> 6;

  float Wr[4], fr[4], cnr[4], csr[4];
#pragma unroll
  for (int e = 0; e < 4; ++e) {
    Wr[e] = (float)W4[t * 4 + e];
    fr[e] = (float)((double)t / 1024.0 + (double)e / 3072.0 - 0.5);
    cnr[e] = 0.0f; csr[e] = 0.0f;
  }
  float om0 = omega_init[0], om1 = omega_init[1], om2 = omega_init[2];
  float pm0 = 0.f, pm1 = 0.f, pm2 = 0.f;
  bool conv = false;

  // ---- plain iteration: no check code can be if-converted in ----
  auto plain_iter = [&]() {
    float p0 = 0.f, p1 = 0.f, p2 = 0.f, p3 = 0.f, p4 = 0.f, p5 = 0.f;
#pragma unroll
    for (int e = 0; e < 4; ++e) {
      const float f = fr[e];
      float a0 = f - om0, a1 = f - om1, a2 = f - om2;
      float d0 = a0 * a0, d1 = a1 * a1, d2 = a2 * a2;
      float w0 = frcp(1.0f + ALPHA_F * (d0 + d1));
      float w1 = frcp(1.0f + ALPHA_F * (d0 + d1 + d2));
      float w2 = frcp(1.0f + ALPHA_F * (d1 + d2));
      float hf = 1.0f - 0.5f * cnr[e];
      float g = hf * hf;
      float gw0 = g * w0 * w0, gw1 = g * w1 * w1, gw2 = g * w2 * w2;
      const float wj = Wr[e];
      p0 += wj * (f * gw0); p1 += wj * (f * gw1); p2 += wj * (f * gw2);
      p3 += wj * gw0;       p4 += wj * gw1;       p5 += wj * gw2;
      float S = w0 + w1 + w2;
      cnr[e] += TAU_F * (S * hf - 1.0f);
    }
    p0 = wave64_sum(p0); p1 = wave64_sum(p1); p2 = wave64_sum(p2);
    p3 = wave64_sum(p3); p4 = wave64_sum(p4); p5 = wave64_sum(p5);
    if (lane == 63) {
      red[0 * 16 + wv] = p0; red[1 * 16 + wv] = p1; red[2 * 16 + wv] = p2;
      red[3 * 16 + wv] = p3; red[4 * 16 + wv] = p4; red[5 * 16 + wv] = p5;
    }
    __syncthreads();
    if (t < 96) {                       // 6 slots x 16 wave-partials
      float v = row16_sum(red[t]);
      if ((t & 15) == 15) sbf[t >> 4] = v;
    }
    __syncthreads();
    om0 = sbf[0] * frcp(sbf[3]);
    om1 = sbf[1] * frcp(sbf[4]);
    om2 = sbf[2] * frcp(sbf[5]);
  };

  // ---- check iteration (n = 10,20,30,40): adds u_diff slots + conv eval ----
  auto check_iter = [&]() {
    float p0 = 0.f, p1 = 0.f, p2 = 0.f, p3 = 0.f, p4 = 0.f, p5 = 0.f,
          p6 = 0.f, p7 = 0.f;
#pragma unroll
    for (int e = 0; e < 4; ++e) {
      const float f = fr[e];
      float a0 = f - om0, a1 = f - om1, a2 = f - om2;
      float d0 = a0 * a0, d1 = a1 * a1, d2 = a2 * a2;
      float w0 = frcp(1.0f + ALPHA_F * (d0 + d1));
      float w1 = frcp(1.0f + ALPHA_F * (d0 + d1 + d2));
      float w2 = frcp(1.0f + ALPHA_F * (d1 + d2));
      float hf = 1.0f - 0.5f * cnr[e];
      float g = hf * hf;
      float gw0 = g * w0 * w0, gw1 = g * w1 * w1, gw2 = g * w2 * w2;
      const float wj = Wr[e];
      p0 += wj * (f * gw0); p1 += wj * (f * gw1); p2 += wj * (f * gw2);
      p3 += wj * gw0;       p4 += wj * gw1;       p5 += wj * gw2;
      float S = w0 + w1 + w2;
      cnr[e] += TAU_F * (S * hf - 1.0f);
      float hp = 1.0f - 0.5f * csr[e];
      float b0 = f - pm0, b1 = f - pm1, b2 = f - pm2;
      float e0 = b0 * b0, e1 = b1 * b1, e2 = b2 * b2;
      float v0 = frcp(1.0f + ALPHA_F * (e0 + e1));
      float v1 = frcp(1.0f + ALPHA_F * (e0 + e1 + e2));
      float v2 = frcp(1.0f + ALPHA_F * (e1 + e2));
      float q0 = hf * w0 - hp * v0;
      float q1 = hf * w1 - hp * v1;
      float q2 = hf * w2 - hp * v2;
      p6 += wj * (q0 * q0 + q1 * q1 + q2 * q2);
      p7 += wj * ((hp * hp) * (v0 * v0 + v1 * v1 + v2 * v2));
    }
    p0 = wave64_sum(p0); p1 = wave64_sum(p1); p2 = wave64_sum(p2);
    p3 = wave64_sum(p3); p4 = wave64_sum(p4); p5 = wave64_sum(p5);
    p6 = wave64_sum(p6); p7 = wave64_sum(p7);
    if (lane == 63) {
      red[0 * 16 + wv] = p0; red[1 * 16 + wv] = p1; red[2 * 16 + wv] = p2;
      red[3 * 16 + wv] = p3; red[4 * 16 + wv] = p4; red[5 * 16 + wv] = p5;
      red[6 * 16 + wv] = p6; red[7 * 16 + wv] = p7;
    }
    __syncthreads();
    if (t < 128) {                      // 8 slots x 16 wave-partials
      float v = row16_sum(red[t]);
      if ((t & 15) == 15) sbf[t >> 4] = v;
    }
    __syncthreads();
    float no0 = sbf[0] * frcp(sbf[3]);
    float no1 = sbf[1] * frcp(sbf[4]);
    float no2 = sbf[2] * frcp(sbf[5]);
    bool ud_ok = sbf[6] < 1e-6f * sbf[7];
    float omd = (fabsf(no0 - no2) + fabsf(no1 - no0) + fabsf(no2 - no1))
                * (1.0f / 3.0f);
    conv = ud_ok && (omd < 1e-6f);
    om0 = no0; om1 = no1; om2 = no2;
  };

  auto keep_store = [&]() {             // entry state of current iteration
    ((float4*)ckeepN)[t] = make_float4(cnr[0], cnr[1], cnr[2], cnr[3]);
    if (t == 0) { omegaF[0] = om0; omegaF[1] = om1; omegaF[2] = om2; }
  };
  auto snap = [&]() {
#pragma unroll
    for (int e = 0; e < 4; ++e) csr[e] = cnr[e];
    pm0 = om0; pm1 = om1; pm2 = om2;
  };

  // ---- group 0: n = 0..9 ----
  plain_iter();                               // n = 0
#pragma unroll 1
  for (int m = 0; m < 8; ++m) plain_iter();   // n = 1..8
  snap();
  plain_iter();                               // n = 9
  // ---- groups 1..4 ----
#pragma unroll 1
  for (int g = 1; g < 5; ++g) {
    keep_store();                             // entry of n = 10g
    check_iter();                             // n = 10g
    if (conv) return;
#pragma unroll 1
    for (int m = 0; m < 8; ++m) plain_iter(); // n = 10g+1 .. 10g+8
    if (g == 4) keep_store();                 // entry of n = 49
    snap();
    plain_iter();                             // n = 10g+9
  }
}

// ---------------- inverse passA: pk=0 -> V0 + i*V1 packed ; pk=1 -> V2 ------
__global__ __launch_bounds__(256) void k_inv_A2(
    const float2* __restrict__ fhat, const float* __restrict__ ckeepN,
    const float* __restrict__ omegaF, float2* __restrict__ ws0)
{
  __shared__ float2 A[PADN2], B[PADN2];
  __shared__ float cn4[4096];
  __shared__ float som[3];
  const int tid = threadIdx.x;
  const int pk = blockIdx.x >> 10;
  const int b = swz(blockIdx.x & 1023);   // k1 of s-layout
  for (int i = tid; i < 4096; i += 256) cn4[i] = ckeepN[i];
  if (tid == 0) { som[0] = omegaF[0]; som[1] = omegaF[1]; som[2] = omegaF[2]; }
  __syncthreads();
  const float om0 = som[0], om1 = som[1], om2 = som[2];
  const float xb = (float)b * (1.0f / 1024.0f);
  float l0, l1, l2, l3, m0, m1, m2, m3;
  lag4(xb, l0, l1, l2, l3);
  lag4(1.0f - xb, m0, m1, m2, m3);

#pragma unroll
  for (int q = 0; q < 4; ++q) {
    int j = tid + 256 * q;       // k2
    float2 f = fhat[(size_t)b * 1024 + j];
    int bin = j ^ 512;
    int binp = 1023 - bin;
    float4 cv = ((const float4*)cn4)[bin];
    float4 cw = ((const float4*)cn4)[binp];
    float c  = l0 * cv.x + l1 * cv.y + l2 * cv.z + l3 * cv.w;
    float cp = m0 * cw.x + m1 * cw.y + m2 * cw.z + m3 * cw.w;
    float hf = 1.0f - 0.5f * c;
    float hp = 1.0f - 0.5f * cp;
    int tt = (bin << 10) | b;
    float freq = (float)tt * (1.0f / 1048576.0f) - 0.5f;
    float a0 = freq - om0, a1 = freq - om1, a2 = freq - om2;
    float d0 = a0 * a0, d1 = a1 * a1, d2 = a2 * a2;
    float g0 = -freq - om0, g1 = -freq - om1, g2 = -freq - om2;
    float e0 = g0 * g0, e1 = g1 * g1, e2 = g2 * g2;
    float2 V;
    if (pk == 0) {
      float r0  = hf * frcp(1.0f + ALPHA_F * (d0 + d1));
      float r0n = hp * frcp(1.0f + ALPHA_F * (e0 + e1));
      float r1  = hf * frcp(1.0f + ALPHA_F * (d0 + d1 + d2));
      float r1n = hp * frcp(1.0f + ALPHA_F * (e0 + e1 + e2));
      float Rr = 0.5f * (r0 + r0n);
      float Ri = 0.5f * (r1 + r1n);
      V = make_float2(f.x * Rr - f.y * Ri, f.x * Ri + f.y * Rr);
    } else {
      float r2  = hf * frcp(1.0f + ALPHA_F * (d1 + d2));
      float r2n = hp * frcp(1.0f + ALPHA_F * (e1 + e2));
      float Rr = 0.5f * (r2 + r2n);
      V = make_float2(f.x * Rr, f.y * Rr);
    }
    A[lpad2(j)] = V;
  }
  __syncthreads();
  fft1024c<1>(A, B);
#pragma unroll
  for (int q = 0; q < 4; ++q) {
    int m1i = tid + 256 * q;
    int ph = b * m1i;
    float s, c;
    sincospif((float)ph * (2.0f / 1048576.0f), &s, &c);
    float2 v = B[lpad2(m1i)];
    ws0[(size_t)pk * 1048576 + (size_t)m1i * 1024 + b]
        = make_float2(v.x * c - v.y * s, v.y * c + v.x * s);
  }
}

// ---------------- inverse passB: pk=0 -> out0=Re,out1=Im ; pk=1 -> out2=Re --
__global__ __launch_bounds__(256) void k_inv_B2(const float2* __restrict__ ws0,
                                                float* __restrict__ out)
{
  __shared__ float2 A[PADN2], B[PADN2];
  const int pk = blockIdx.x >> 10;
  const int b = swz(blockIdx.x & 1023);   // m1
  const int tid = threadIdx.x;
#pragma unroll
  for (int q = 0; q < 4; ++q) {
    int j = tid + 256 * q;       // contiguous read of row m1=b
    A[lpad2(j)] = ws0[(size_t)pk * 1048576 + (size_t)b * 1024 + j];
  }
  __syncthreads();
  fft1024c<1>(A, B);
  const float sc = 1.0f / 1048576.0f;
#pragma unroll
  for (int q = 0; q < 4; ++q) {
    int m2 = tid + 256 * q;
    float2 v = B[lpad2(m2)];
    if (pk == 0) {
      out[(size_t)m2 * 1024 + b]           = v.x * sc;   // imf0
      out[1048576 + (size_t)m2 * 1024 + b] = v.y * sc;   // imf1
    } else {
      out[2097152 + (size_t)m2 * 1024 + b] = v.x * sc;   // imf2
    }
  }
}

// ---------------- host launch ----------------
extern "C" void kernel_launch(void* const* d_in, const int* in_sizes, int n_in,
                              void* d_out, int out_size, void* d_ws, size_t ws_size,
                              hipStream_t stream)
{
  (void)in_sizes; (void)n_in; (void)out_size; (void)ws_size;
  const float* x       = (const float*)d_in[0];
  const float* om_init = (const float*)d_in[1];
  float* out = (float*)d_out;

  char* w = (char*)d_ws;
  const size_t MB = 1024ull * 1024ull;
  float2* fhat     = (float2*)(w);
  float*  E        = (float*)(w + 8 * MB);
  double* W4       = (double*)(w + 12 * MB);            // 4096 doubles (32 KB)
  float*  ckeepN   = (float*)(w + 12 * MB + 32 * 1024); // 4096 floats
  float*  omegaF   = (float*)(w + 12 * MB + 48 * 1024);
  float2* scratch  = (float2*)(w + 16 * MB);            // 2 x 8 MB

  k_fwd_passA<<<1024, 256, 0, stream>>>(x, scratch);
  k_fwd_passB<<<1024, 256, 0, stream>>>(scratch, fhat, E);
  k_moments<<<1024, 256, 0, stream>>>(E, W4);
  k_solve<<<1, 1024, 0, stream>>>(W4, om_init, ckeepN, omegaF);
  k_inv_A2<<<2048, 256, 0, stream>>>(fhat, ckeepN, omegaF, scratch);
  k_inv_B2<<<2048, 256, 0, stream>>>(scratch, out);
}

// Round 12
// 195.984 us; speedup vs baseline: 9.1022x; 1.0825x over previous
//
#include <hip/hip_runtime.h>
#include <math.h>

// VMD: T = 2^20, K = 3, 50 iterations.
// Round-12: (1) passA = packed-real 2-column FFT (512 blocks): z=x0+i*x1,
// Hermitian split -> halves FFT work AND strided line-touches.
// (2) passB stores E TRANSPOSED (strided stores are fire-and-forget) so
// k_moments reads contiguously -- bit-identical W, kills its strided loads.
// (3) k_solve: 512 thr x 8 nodes -- 8 waves (cheaper barriers/stage2), more
// ILP to hide rcp latency.
// Workspace (~40 MB of ~256 MB):
//   [0,8MB)   f_hat (float2, s-layout: s = k1*1024+k2, t(s) = ((k2^512)<<10)|k1)
//   [8,12MB)  ET = |f_hat|^2 transposed: ET[k2*1024 + k1] (float)
//   [12MB..)  W f64[1024*4]; ckeepN float[4096]; omegaF float[4]
//   [16,32MB) scratch (2 x 8MB float2) -- FFT intermediates

#define ALPHA_F 2000.0f
#define TAU_F   1e-7f

static __device__ __forceinline__ int lpad2(int i) { return i + (i >> 4); }
static __device__ __forceinline__ int swz(int i)  { return ((i & 7) << 7) | (i >> 3); }
static __device__ __forceinline__ int swzA(int i) { return ((i & 7) << 6) | (i >> 3); }
static __device__ __forceinline__ float frcp(float x) { return __builtin_amdgcn_rcpf(x); }

#define PADN2 1088

// ---------------- DPP reductions (VALU pipe only) ----------------
template<int CTRL>
static __device__ __forceinline__ float dpp_addf(float v)
{
  int r = __builtin_amdgcn_update_dpp(0, __float_as_int(v), CTRL, 0xf, 0xf, true);
  return v + __int_as_float(r);
}
static __device__ __forceinline__ float wave64_sum(float v)
{
  v = dpp_addf<0x111>(v);   // row_shr:1
  v = dpp_addf<0x112>(v);   // row_shr:2
  v = dpp_addf<0x114>(v);   // row_shr:4
  v = dpp_addf<0x118>(v);   // row_shr:8
  v = dpp_addf<0x142>(v);   // row_bcast:15
  v = dpp_addf<0x143>(v);   // row_bcast:31 -> lane 63 = full sum
  return v;
}
static __device__ __forceinline__ float row16_sum(float v)
{
  v = dpp_addf<0x111>(v);
  v = dpp_addf<0x112>(v);
  v = dpp_addf<0x114>(v);
  v = dpp_addf<0x118>(v);   // lane 15 of each 16-lane row = row sum
  return v;
}

// ---------------- 1024-point radix-4 Stockham FFT, float2 LDS ----------------
template<int SIGN>   // -1 = forward (e^{-i}), +1 = inverse (e^{+i}, unscaled)
static __device__ void fft1024c(float2* A, float2* B)   // in A, out B
{
  const int u = threadIdx.x;
#pragma unroll
  for (int st = 0; st < 5; ++st) {
    float2 *in  = (st & 1) ? B : A;
    float2 *out = (st & 1) ? A : B;
    const int quarter = 1 << (2 * st);
    const int p = u & (quarter - 1);
    const int g = u >> (2 * st);

    float w1r, w1i;
    if (st == 0) { w1r = 1.0f; w1i = 0.0f; }
    else {
      float sw, cw;
      sincospif((float)(2 * p) * (1.0f / (float)(4 << (2 * st))), &sw, &cw);
      w1r = cw; w1i = (SIGN < 0) ? -sw : sw;
    }
    const float w2r = w1r*w1r - w1i*w1i,  w2i = 2.0f*w1r*w1i;
    const float w3r = w2r*w1r - w2i*w1i,  w3i = w2r*w1i + w2i*w1r;

    float2 X0 = in[lpad2(u      )];
    float2 X1 = in[lpad2(u + 256)];
    float2 X2 = in[lpad2(u + 512)];
    float2 X3 = in[lpad2(u + 768)];

    float y1r = X1.x*w1r - X1.y*w1i, y1i = X1.x*w1i + X1.y*w1r;
    float y2r = X2.x*w2r - X2.y*w2i, y2i = X2.x*w2i + X2.y*w2r;
    float y3r = X3.x*w3r - X3.y*w3i, y3i = X3.x*w3i + X3.y*w3r;

    float t0r = X0.x + y2r, t0i = X0.y + y2i;
    float t1r = X0.x - y2r, t1i = X0.y - y2i;
    float t2r = y1r + y3r,  t2i = y1i + y3i;
    float t3r = y1r - y3r,  t3i = y1i - y3i;

    float o0r = t0r + t2r, o0i = t0i + t2i;
    float o2r = t0r - t2r, o2i = t0i - t2i;
    float o1r, o1i, o3r, o3i;
    if (SIGN < 0) {
      o1r = t1r + t3i; o1i = t1i - t3r;
      o3r = t1r - t3i; o3i = t1i + t3r;
    } else {
      o1r = t1r - t3i; o1i = t1i + t3r;
      o3r = t1r + t3i; o3i = t1i - t3r;
    }
    const int base = (g << (2 * st + 2)) + p;
    out[lpad2(base              )] = make_float2(o0r, o0i);
    out[lpad2(base +     quarter)] = make_float2(o1r, o1i);
    out[lpad2(base + 2 * quarter)] = make_float2(o2r, o2i);
    out[lpad2(base + 3 * quarter)] = make_float2(o3r, o3i);
    __syncthreads();
  }
}

// ---------------- forward passA: packed-real, 2 columns per block ----------
// z_j = x[j][2p] + i*x[j][2p+1]; after FFT, Hermitian split recovers both
// column spectra; twiddle each; one float4 store writes both.
__global__ __launch_bounds__(256) void k_fwd_passA(const float* __restrict__ x,
                                                   float2* __restrict__ ws0)
{
  __shared__ float2 A[PADN2], B[PADN2];
  const int p = swzA(blockIdx.x);     // 512 blocks; column pair (2p, 2p+1)
  const int tid = threadIdx.x;
  const int c0 = 2 * p;
#pragma unroll
  for (int q = 0; q < 4; ++q) {
    int j = tid + 256 * q;            // n1
    A[lpad2(j)] = ((const float2*)x)[(size_t)j * 512 + p];
  }
  __syncthreads();
  fft1024c<-1>(A, B);
#pragma unroll
  for (int q = 0; q < 4; ++q) {
    int k = tid + 256 * q;
    int kk = (1024 - k) & 1023;
    float2 Z = B[lpad2(k)];
    float2 Wv = B[lpad2(kk)];
    // X0 = (Z + conj(W))/2 ; X1 = (Z - conj(W))/(2i)
    float X0r = 0.5f * (Z.x + Wv.x), X0i = 0.5f * (Z.y - Wv.y);
    float X1r = 0.5f * (Z.y + Wv.y), X1i = 0.5f * (Wv.x - Z.x);
    int ph0 = c0 * k;                 // < 2^21, exact in fp32
    int ph1 = ph0 + k;
    float s0, cc0, s1, cc1;
    sincospif((float)ph0 * (2.0f / 1048576.0f), &s0, &cc0);
    sincospif((float)ph1 * (2.0f / 1048576.0f), &s1, &cc1);
    float4 o;                         // multiply by e^{-i*2pi*ph/2^20}
    o.x = X0r * cc0 + X0i * s0; o.y = X0i * cc0 - X0r * s0;
    o.z = X1r * cc1 + X1i * s1; o.w = X1i * cc1 - X1r * s1;
    ((float4*)ws0)[(size_t)k * 512 + p] = o;   // ws0[k*1024 + c0 .. c0+1]
  }
}

// ---------------- forward passB: contiguous reads; stores fhat + E^T --------
__global__ __launch_bounds__(256) void k_fwd_passB(const float2* __restrict__ ws0,
                                                   float2* __restrict__ fhat,
                                                   float* __restrict__ ET)
{
  __shared__ float2 A[PADN2], B[PADN2];
  const int b = swz(blockIdx.x);   // k1
  const int tid = threadIdx.x;
#pragma unroll
  for (int q = 0; q < 4; ++q) {
    int j = tid + 256 * q;         // n2 ; contiguous read
    A[lpad2(j)] = ws0[(size_t)b * 1024 + j];
  }
  __syncthreads();
  fft1024c<-1>(A, B);
#pragma unroll
  for (int q = 0; q < 4; ++q) {
    int k2 = tid + 256 * q;
    float2 v = B[lpad2(k2)];
    fhat[(size_t)b * 1024 + k2] = v;
    ET[(size_t)k2 * 1024 + b] = v.x * v.x + v.y * v.y;  // strided store (cheap)
  }
}

// ---------------- Lagrange basis on nodes x = {0, 1/3, 2/3, 1} --------------
static __device__ __forceinline__ void lag4(float x, float& l0, float& l1,
                                            float& l2, float& l3)
{
  float m0 = x, m1 = x - (1.0f / 3.0f), m2 = x - (2.0f / 3.0f), m3 = x - 1.0f;
  l0 = -4.5f * m1 * m2 * m3;
  l1 = 13.5f * m0 * m2 * m3;
  l2 = -13.5f * m0 * m1 * m3;
  l3 =  4.5f * m0 * m1 * m2;
}

// ---------------- bin weights from E^T (fully contiguous reads) -------------
__global__ __launch_bounds__(256) void k_moments(const float* __restrict__ ET,
                                                 double* __restrict__ W)
{
  __shared__ double red[4 * 4];
  const int B = blockIdx.x;        // bin
  const int k2 = B ^ 512;
  const int tid = threadIdx.x;
  double a0 = 0, a1 = 0, a2 = 0, a3 = 0;
#pragma unroll
  for (int q = 0; q < 4; ++q) {
    int k1 = tid + 256 * q;
    float e = ET[(size_t)k2 * 1024 + k1];   // contiguous
    float l0, l1, l2, l3;
    lag4((float)k1 * (1.0f / 1024.0f), l0, l1, l2, l3);
    a0 += (double)(e * l0); a1 += (double)(e * l1);
    a2 += (double)(e * l2); a3 += (double)(e * l3);
  }
  const int lane = tid & 63, wv = tid >> 6;       // 4 waves
  double pv[4] = { a0, a1, a2, a3 };
#pragma unroll
  for (int j = 0; j < 4; ++j) {
    double v = pv[j];
    for (int off = 32; off; off >>= 1) v += __shfl_down(v, off, 64);
    if (lane == 0) red[wv * 4 + j] = v;
  }
  __syncthreads();
  if (tid < 4)
    W[B * 4 + tid] = red[tid] + red[4 + tid] + red[8 + tid] + red[12 + tid];
}

// ---------------- the whole 50-iteration loop in ONE workgroup --------------
// 512 threads; thread t owns bins 2t, 2t+1 (8 cubic nodes). Peeled bodies.
__global__ __launch_bounds__(512) void k_solve(
    const double* __restrict__ W4, const float* __restrict__ omega_init,
    float* __restrict__ ckeepN, float* __restrict__ omegaF)
{
  __shared__ float red[8 * 16];    // [slot][16]; only idx 0..7 written, rest 0
  __shared__ float sbf[8];
  const int t = threadIdx.x;
  const int lane = t & 63, wv = t >> 6;    // 8 waves

  for (int i = t; i < 8 * 16; i += 512) red[i] = 0.0f;

  float Wr[8], fr[8], cnr[8], csr[8];
#pragma unroll
  for (int e = 0; e < 8; ++e) {
    Wr[e] = (float)W4[t * 8 + e];
    int bin = 2 * t + (e >> 2);
    fr[e] = (float)((double)bin / 1024.0 + (double)(e & 3) / 3072.0 - 0.5);
    cnr[e] = 0.0f; csr[e] = 0.0f;
  }
  float om0 = omega_init[0], om1 = omega_init[1], om2 = omega_init[2];
  float pm0 = 0.f, pm1 = 0.f, pm2 = 0.f;
  bool conv = false;
  __syncthreads();

  auto plain_iter = [&]() {
    float p0 = 0.f, p1 = 0.f, p2 = 0.f, p3 = 0.f, p4 = 0.f, p5 = 0.f;
#pragma unroll
    for (int e = 0; e < 8; ++e) {
      const float f = fr[e];
      float a0 = f - om0, a1 = f - om1, a2 = f - om2;
      float d0 = a0 * a0, d1 = a1 * a1, d2 = a2 * a2;
      float w0 = frcp(1.0f + ALPHA_F * (d0 + d1));
      float w1 = frcp(1.0f + ALPHA_F * (d0 + d1 + d2));
      float w2 = frcp(1.0f + ALPHA_F * (d1 + d2));
      float hf = 1.0f - 0.5f * cnr[e];
      float g = hf * hf;
      float gw0 = g * w0 * w0, gw1 = g * w1 * w1, gw2 = g * w2 * w2;
      const float wj = Wr[e];
      p0 += wj * (f * gw0); p1 += wj * (f * gw1); p2 += wj * (f * gw2);
      p3 += wj * gw0;       p4 += wj * gw1;       p5 += wj * gw2;
      float S = w0 + w1 + w2;
      cnr[e] += TAU_F * (S * hf - 1.0f);
    }
    p0 = wave64_sum(p0); p1 = wave64_sum(p1); p2 = wave64_sum(p2);
    p3 = wave64_sum(p3); p4 = wave64_sum(p4); p5 = wave64_sum(p5);
    if (lane == 63) {
      red[0 * 16 + wv] = p0; red[1 * 16 + wv] = p1; red[2 * 16 + wv] = p2;
      red[3 * 16 + wv] = p3; red[4 * 16 + wv] = p4; red[5 * 16 + wv] = p5;
    }
    __syncthreads();
    if (t < 96) {                       // 6 slots x 16 (upper 8 are zeros)
      float v = row16_sum(red[t]);
      if ((t & 15) == 15) sbf[t >> 4] = v;
    }
    __syncthreads();
    om0 = sbf[0] * frcp(sbf[3]);
    om1 = sbf[1] * frcp(sbf[4]);
    om2 = sbf[2] * frcp(sbf[5]);
  };

  auto check_iter = [&]() {
    float p0 = 0.f, p1 = 0.f, p2 = 0.f, p3 = 0.f, p4 = 0.f, p5 = 0.f,
          p6 = 0.f, p7 = 0.f;
#pragma unroll
    for (int e = 0; e < 8; ++e) {
      const float f = fr[e];
      float a0 = f - om0, a1 = f - om1, a2 = f - om2;
      float d0 = a0 * a0, d1 = a1 * a1, d2 = a2 * a2;
      float w0 = frcp(1.0f + ALPHA_F * (d0 + d1));
      float w1 = frcp(1.0f + ALPHA_F * (d0 + d1 + d2));
      float w2 = frcp(1.0f + ALPHA_F * (d1 + d2));
      float hf = 1.0f - 0.5f * cnr[e];
      float g = hf * hf;
      float gw0 = g * w0 * w0, gw1 = g * w1 * w1, gw2 = g * w2 * w2;
      const float wj = Wr[e];
      p0 += wj * (f * gw0); p1 += wj * (f * gw1); p2 += wj * (f * gw2);
      p3 += wj * gw0;       p4 += wj * gw1;       p5 += wj * gw2;
      float S = w0 + w1 + w2;
      cnr[e] += TAU_F * (S * hf - 1.0f);
      float hp = 1.0f - 0.5f * csr[e];
      float b0 = f - pm0, b1 = f - pm1, b2 = f - pm2;
      float e0 = b0 * b0, e1 = b1 * b1, e2 = b2 * b2;
      float v0 = frcp(1.0f + ALPHA_F * (e0 + e1));
      float v1 = frcp(1.0f + ALPHA_F * (e0 + e1 + e2));
      float v2 = frcp(1.0f + ALPHA_F * (e1 + e2));
      float q0 = hf * w0 - hp * v0;
      float q1 = hf * w1 - hp * v1;
      float q2 = hf * w2 - hp * v2;
      p6 += wj * (q0 * q0 + q1 * q1 + q2 * q2);
      p7 += wj * ((hp * hp) * (v0 * v0 + v1 * v1 + v2 * v2));
    }
    p0 = wave64_sum(p0); p1 = wave64_sum(p1); p2 = wave64_sum(p2);
    p3 = wave64_sum(p3); p4 = wave64_sum(p4); p5 = wave64_sum(p5);
    p6 = wave64_sum(p6); p7 = wave64_sum(p7);
    if (lane == 63) {
      red[0 * 16 + wv] = p0; red[1 * 16 + wv] = p1; red[2 * 16 + wv] = p2;
      red[3 * 16 + wv] = p3; red[4 * 16 + wv] = p4; red[5 * 16 + wv] = p5;
      red[6 * 16 + wv] = p6; red[7 * 16 + wv] = p7;
    }
    __syncthreads();
    if (t < 128) {                      // 8 slots x 16
      float v = row16_sum(red[t]);
      if ((t & 15) == 15) sbf[t >> 4] = v;
    }
    __syncthreads();
    float no0 = sbf[0] * frcp(sbf[3]);
    float no1 = sbf[1] * frcp(sbf[4]);
    float no2 = sbf[2] * frcp(sbf[5]);
    bool ud_ok = sbf[6] < 1e-6f * sbf[7];
    float omd = (fabsf(no0 - no2) + fabsf(no1 - no0) + fabsf(no2 - no1))
                * (1.0f / 3.0f);
    conv = ud_ok && (omd < 1e-6f);
    om0 = no0; om1 = no1; om2 = no2;
  };

  auto keep_store = [&]() {             // entry state of current iteration
    ((float4*)ckeepN)[2 * t]     = make_float4(cnr[0], cnr[1], cnr[2], cnr[3]);
    ((float4*)ckeepN)[2 * t + 1] = make_float4(cnr[4], cnr[5], cnr[6], cnr[7]);
    if (t == 0) { omegaF[0] = om0; omegaF[1] = om1; omegaF[2] = om2; }
  };
  auto snap = [&]() {
#pragma unroll
    for (int e = 0; e < 8; ++e) csr[e] = cnr[e];
    pm0 = om0; pm1 = om1; pm2 = om2;
  };

  // ---- group 0: n = 0..9 ----
  plain_iter();                               // n = 0
#pragma unroll 1
  for (int m = 0; m < 8; ++m) plain_iter();   // n = 1..8
  snap();
  plain_iter();                               // n = 9
  // ---- groups 1..4 ----
#pragma unroll 1
  for (int g = 1; g < 5; ++g) {
    keep_store();                             // entry of n = 10g
    check_iter();                             // n = 10g
    if (conv) return;
#pragma unroll 1
    for (int m = 0; m < 8; ++m) plain_iter(); // n = 10g+1 .. 10g+8
    if (g == 4) keep_store();                 // entry of n = 49
    snap();
    plain_iter();                             // n = 10g+9
  }
}

// ---------------- inverse passA: pk=0 -> V0 + i*V1 packed ; pk=1 -> V2 ------
__global__ __launch_bounds__(256) void k_inv_A2(
    const float2* __restrict__ fhat, const float* __restrict__ ckeepN,
    const float* __restrict__ omegaF, float2* __restrict__ ws0)
{
  __shared__ float2 A[PADN2], B[PADN2];
  __shared__ float cn4[4096];
  __shared__ float som[3];
  const int tid = threadIdx.x;
  const int pk = blockIdx.x >> 10;
  const int b = swz(blockIdx.x & 1023);   // k1 of s-layout
  for (int i = tid; i < 4096; i += 256) cn4[i] = ckeepN[i];
  if (tid == 0) { som[0] = omegaF[0]; som[1] = omegaF[1]; som[2] = omegaF[2]; }
  __syncthreads();
  const float om0 = som[0], om1 = som[1], om2 = som[2];
  const float xb = (float)b * (1.0f / 1024.0f);
  float l0, l1, l2, l3, m0, m1, m2, m3;
  lag4(xb, l0, l1, l2, l3);
  lag4(1.0f - xb, m0, m1, m2, m3);

#pragma unroll
  for (int q = 0; q < 4; ++q) {
    int j = tid + 256 * q;       // k2
    float2 f = fhat[(size_t)b * 1024 + j];
    int bin = j ^ 512;
    int binp = 1023 - bin;
    float4 cv = ((const float4*)cn4)[bin];
    float4 cw = ((const float4*)cn4)[binp];
    float c  = l0 * cv.x + l1 * cv.y + l2 * cv.z + l3 * cv.w;
    float cp = m0 * cw.x + m1 * cw.y + m2 * cw.z + m3 * cw.w;
    float hf = 1.0f - 0.5f * c;
    float hp = 1.0f - 0.5f * cp;
    int tt = (bin << 10) | b;
    float freq = (float)tt * (1.0f / 1048576.0f) - 0.5f;
    float a0 = freq - om0, a1 = freq - om1, a2 = freq - om2;
    float d0 = a0 * a0, d1 = a1 * a1, d2 = a2 * a2;
    float g0 = -freq - om0, g1 = -freq - om1, g2 = -freq - om2;
    float e0 = g0 * g0, e1 = g1 * g1, e2 = g2 * g2;
    float2 V;
    if (pk == 0) {
      float r0  = hf * frcp(1.0f + ALPHA_F * (d0 + d1));
      float r0n = hp * frcp(1.0f + ALPHA_F * (e0 + e1));
      float r1  = hf * frcp(1.0f + ALPHA_F * (d0 + d1 + d2));
      float r1n = hp * frcp(1.0f + ALPHA_F * (e0 + e1 + e2));
      float Rr = 0.5f * (r0 + r0n);
      float Ri = 0.5f * (r1 + r1n);
      V = make_float2(f.x * Rr - f.y * Ri, f.x * Ri + f.y * Rr);
    } else {
      float r2  = hf * frcp(1.0f + ALPHA_F * (d1 + d2));
      float r2n = hp * frcp(1.0f + ALPHA_F * (e1 + e2));
      float Rr = 0.5f * (r2 + r2n);
      V = make_float2(f.x * Rr, f.y * Rr);
    }
    A[lpad2(j)] = V;
  }
  __syncthreads();
  fft1024c<1>(A, B);
#pragma unroll
  for (int q = 0; q < 4; ++q) {
    int m1i = tid + 256 * q;
    int ph = b * m1i;
    float s, c;
    sincospif((float)ph * (2.0f / 1048576.0f), &s, &c);
    float2 v = B[lpad2(m1i)];
    ws0[(size_t)pk * 1048576 + (size_t)m1i * 1024 + b]
        = make_float2(v.x * c - v.y * s, v.y * c + v.x * s);
  }
}

// ---------------- inverse passB: pk=0 -> out0=Re,out1=Im ; pk=1 -> out2=Re --
__global__ __launch_bounds__(256) void k_inv_B2(const float2* __restrict__ ws0,
                                                float* __restrict__ out)
{
  __shared__ float2 A[PADN2], B[PADN2];
  const int pk = blockIdx.x >> 10;
  const int b = swz(blockIdx.x & 1023);   // m1
  const int tid = threadIdx.x;
#pragma unroll
  for (int q = 0; q < 4; ++q) {
    int j = tid + 256 * q;       // contiguous read of row m1=b
    A[lpad2(j)] = ws0[(size_t)pk * 1048576 + (size_t)b * 1024 + j];
  }
  __syncthreads();
  fft1024c<1>(A, B);
  const float sc = 1.0f / 1048576.0f;
#pragma unroll
  for (int q = 0; q < 4; ++q) {
    int m2 = tid + 256 * q;
    float2 v = B[lpad2(m2)];
    if (pk == 0) {
      out[(size_t)m2 * 1024 + b]           = v.x * sc;   // imf0
      out[1048576 + (size_t)m2 * 1024 + b] = v.y * sc;   // imf1
    } else {
      out[2097152 + (size_t)m2 * 1024 + b] = v.x * sc;   // imf2
    }
  }
}

// ---------------- host launch ----------------
extern "C" void kernel_launch(void* const* d_in, const int* in_sizes, int n_in,
                              void* d_out, int out_size, void* d_ws, size_t ws_size,
                              hipStream_t stream)
{
  (void)in_sizes; (void)n_in; (void)out_size; (void)ws_size;
  const float* x       = (const float*)d_in[0];
  const float* om_init = (const float*)d_in[1];
  float* out = (float*)d_out;

  char* w = (char*)d_ws;
  const size_t MB = 1024ull * 1024ull;
  float2* fhat     = (float2*)(w);
  float*  ET       = (float*)(w + 8 * MB);
  double* W4       = (double*)(w + 12 * MB);            // 4096 doubles (32 KB)
  float*  ckeepN   = (float*)(w + 12 * MB + 32 * 1024); // 4096 floats
  float*  omegaF   = (float*)(w + 12 * MB + 48 * 1024);
  float2* scratch  = (float2*)(w + 16 * MB);            // 2 x 8 MB

  k_fwd_passA<<<512, 256, 0, stream>>>(x, scratch);
  k_fwd_passB<<<1024, 256, 0, stream>>>(scratch, fhat, ET);
  k_moments<<<1024, 256, 0, stream>>>(ET, W4);
  k_solve<<<1, 512, 0, stream>>>(W4, om_init, ckeepN, omegaF);
  k_inv_A2<<<2048, 256, 0, stream>>>(fhat, ckeepN, omegaF, scratch);
  k_inv_B2<<<2048, 256, 0, stream>>>(scratch, out);
}